// Round 4
// baseline (283.185 us; speedup 1.0000x reference)
//
#include <hip/hip_runtime.h>
#include <stdint.h>

// Attention fwd: B=4 T=2048 D=1024 H=16 Dh=64.
// R12: (1) flash KVBLK 64->128: 2 buffers x (K 16KB + V 16KB) = 64KB LDS,
//   16 barrier periods instead of 32 (halves lockstep drains, 4 independent
//   blk-chains per period) + setprio(1) around PV MFMA cluster (T5, m191).
//   (2) gemm_qkv XCD swizzle REVERTED to R9 plain mapping (R11's chunk put
//   8MB/XCD > 4MB L2 - arithmetic error). gemm_o keeps 128x128 + swizzle
//   (2+2MB/XCD = L2-fit). flash was 73us = 941 TF, ~5x stall factor vs
//   issue model -> barrier-cadence theory; if >=70 next round, theory dead.

typedef __attribute__((ext_vector_type(8))) short bf16x8;
typedef __attribute__((ext_vector_type(4))) float f32x4;

#define MFMA32 __builtin_amdgcn_mfma_f32_16x16x32_bf16

#if __has_builtin(__builtin_amdgcn_exp2f)
#define EXP2(x) __builtin_amdgcn_exp2f(x)
#else
#define EXP2(x) exp2f(x)   // host pass only
#endif

__device__ __forceinline__ unsigned short f2bf(float f) {
  union { float f; unsigned int u; } v; v.f = f;
  unsigned int r = v.u + 0x7FFFu + ((v.u >> 16) & 1u);  // RNE
  return (unsigned short)(r >> 16);
}

__device__ __forceinline__ void gl_lds16(const void* g, void* l) {
  __builtin_amdgcn_global_load_lds(
      (const __attribute__((address_space(1))) unsigned int*)g,
      (__attribute__((address_space(3))) unsigned int*)l, 16, 0, 0);
}

// truncating pack of two positive fp32 -> one u32 (two bf16)
__device__ __forceinline__ unsigned packbf2(float lo, float hi) {
  union { float f; unsigned u; } a, b; a.f = lo; b.f = hi;
  return __builtin_amdgcn_perm(b.u, a.u, 0x07060302u);
}

// LDS chunk swizzle for K tiles (conflict-free for permuted-row b128 reads)
__device__ __forceinline__ int rho(int r) { return (r & 3) | ((r >> 1) & 4); }

// ---------------- merged prep kernel ----------------
__device__ __forceinline__ void conv8(const float* __restrict__ src,
                                      unsigned short* __restrict__ dst, int i) {
  const float4* sp = (const float4*)src;
  float4 a = sp[2 * i], b = sp[2 * i + 1];
  union { unsigned short u[8]; uint4 v; } o;
  o.u[0] = f2bf(a.x); o.u[1] = f2bf(a.y); o.u[2] = f2bf(a.z); o.u[3] = f2bf(a.w);
  o.u[4] = f2bf(b.x); o.u[5] = f2bf(b.y); o.u[6] = f2bf(b.z); o.u[7] = f2bf(b.w);
  ((uint4*)dst)[i] = o.v;
}

__global__ __launch_bounds__(256) void prep_all(
    const float* __restrict__ x, const float* __restrict__ WQ,
    const float* __restrict__ WK, const float* __restrict__ WV,
    const float* __restrict__ WO, unsigned short* __restrict__ Xb,
    unsigned short* __restrict__ Wqkv, unsigned short* __restrict__ Wot) {
  const int bx = blockIdx.x, t = threadIdx.x;
  if (bx < 4096) {
    conv8(x, Xb, bx * 256 + t);
  } else if (bx < 4608) {
    conv8(WQ, Wqkv, (bx - 4096) * 256 + t);
  } else if (bx < 5120) {
    conv8(WK, Wqkv + 1048576, (bx - 4608) * 256 + t);
  } else if (bx < 5632) {
    conv8(WV, Wqkv + 2097152, (bx - 5120) * 256 + t);
  } else {
    // W_O [16][1024][64] fp32 -> Wot [d][h*64+k] bf16
    int tid = (bx - 5632) * 256 + t;
    int h = tid >> 13, rem = tid & 8191;
    int d = rem >> 3, c = rem & 7;
    const float4* sp = (const float4*)(WO + (size_t)h * 65536 + d * 64 + c * 8);
    float4 a = sp[0], e = sp[1];
    union { unsigned short u[8]; uint4 v; } o;
    o.u[0] = f2bf(a.x); o.u[1] = f2bf(a.y); o.u[2] = f2bf(a.z); o.u[3] = f2bf(a.w);
    o.u[4] = f2bf(e.x); o.u[5] = f2bf(e.y); o.u[6] = f2bf(e.z); o.u[7] = f2bf(e.w);
    *(uint4*)(Wot + (size_t)d * 1024 + h * 64 + c * 8) = o.v;
  }
}

// ---------------- shared GEMM mainloop (128x128, 2-barrier; for gemm_o) -------
__device__ __forceinline__ void gemm_mainloop_1024(
    const unsigned short* __restrict__ A, const unsigned short* __restrict__ B,
    unsigned short* As, unsigned short* Bs, int m0, int n0, f32x4 acc[4][4]) {
  const int tid = threadIdx.x;
  const int lane = tid & 63, w = tid >> 6;
  const int quad = lane >> 4, l15 = lane & 15;
  const int wm = w & 1, wn = w >> 1;
  int srow[4], scl[4];
#pragma unroll
  for (int u = 0; u < 4; ++u) {
    int s = u * 256 + tid;
    srow[u] = s >> 3;
    scl[u] = ((s & 7) ^ ((s >> 3) & 7)) * 8;
  }
  for (int k0 = 0; k0 < 1024; k0 += 64) {
    __syncthreads();
#pragma unroll
    for (int u = 0; u < 4; ++u) {
      int s = u * 256 + tid;
      gl_lds16(A + (size_t)(m0 + srow[u]) * 1024 + k0 + scl[u], As + s * 8);
      gl_lds16(B + (size_t)(n0 + srow[u]) * 1024 + k0 + scl[u], Bs + s * 8);
    }
    __syncthreads();
    bf16x8 af[4][2], bfr[4][2];
#pragma unroll
    for (int i = 0; i < 4; ++i) {
      int ra = wm * 64 + i * 16 + l15;
      int rb = wn * 64 + i * 16 + l15;
#pragma unroll
      for (int c = 0; c < 2; ++c) {
        af[i][c]  = *(const bf16x8*)(As + ra * 64 + (((c * 4 + quad) ^ (ra & 7)) * 8));
        bfr[i][c] = *(const bf16x8*)(Bs + rb * 64 + (((c * 4 + quad) ^ (rb & 7)) * 8));
      }
    }
#pragma unroll
    for (int mi = 0; mi < 4; ++mi)
#pragma unroll
      for (int nj = 0; nj < 4; ++nj) {
        acc[mi][nj] = MFMA32(af[mi][0], bfr[nj][0], acc[mi][nj], 0, 0, 0);
        acc[mi][nj] = MFMA32(af[mi][1], bfr[nj][1], acc[mi][nj], 0, 0, 0);
      }
  }
}

// ---------------- QKV projection: 256x192 tile, 8-phase pipelined ----------------
// LDS ushort layout: A0 @0 (256x64), B0 @16384 (192x64), A1 @28672, B1 @45056.
// Swizzle: element (row,k) at row*64 + ((k>>3)^(row&7))*8 + (k&7)  (involution,
// staged via pre-swizzled global source; measured 0 bank conflicts in R4..R8).

template <int MH, int C>
__device__ __forceinline__ void qkv_ds_a(const unsigned short* A, int wm, int quad,
                                         int l15, bf16x8 ar[4][2]) {
#pragma unroll
  for (int ii = 0; ii < 4; ++ii) {
    int ra = wm * 128 + MH * 64 + ii * 16 + l15;
    ar[ii][C] = *(const bf16x8*)(A + ra * 64 + (((C * 4 + quad) ^ (ra & 7)) * 8));
  }
}

template <int C>
__device__ __forceinline__ void qkv_ds_b(const unsigned short* B, int wn, int quad,
                                         int l15, bf16x8 br[3][2]) {
#pragma unroll
  for (int nj = 0; nj < 3; ++nj) {
    int rb = wn * 48 + nj * 16 + l15;
    br[nj][C] = *(const bf16x8*)(B + rb * 64 + (((C * 4 + quad) ^ (rb & 7)) * 8));
  }
}

template <int MH, int C>
__device__ __forceinline__ void qkv_mf(const bf16x8 ar[4][2], const bf16x8 br[3][2],
                                       f32x4 acc[8][3]) {
#pragma unroll
  for (int ii = 0; ii < 4; ++ii)
#pragma unroll
    for (int nj = 0; nj < 3; ++nj)
      acc[MH * 4 + ii][nj] =
          MFMA32(ar[ii][C], br[nj][C], acc[MH * 4 + ii][nj], 0, 0, 0);
}

#define QKV_BAR() __builtin_amdgcn_s_barrier()
#define QKV_LGKM0() asm volatile("s_waitcnt lgkmcnt(0)" ::: "memory")
#define SA_(bb, kt, u) \
  gl_lds16(Xb + (size_t)aoff[u] + (size_t)(kt) * 64, lds + (bb)*28672 + adst[u])
#define SB_(bb, kt, u) \
  gl_lds16(Wqkv + (size_t)boff[u] + (size_t)(kt) * 64, lds + (bb)*28672 + 16384 + bdst[u])

__global__ __launch_bounds__(512, 2) void gemm_qkv(
    const unsigned short* __restrict__ Xb, const unsigned short* __restrict__ Wqkv,
    const float* __restrict__ bQ, const float* __restrict__ bK,
    const float* __restrict__ bV, unsigned short* __restrict__ Qg,
    unsigned short* __restrict__ Kg, unsigned int* __restrict__ Vpg) {
  __shared__ unsigned short lds[57344];  // 112 KB
  const int tid = threadIdx.x, lane = tid & 63, w = tid >> 6;
  const int quad = lane >> 4, l15 = lane & 15;
  const int wm = w >> 2, wn = w & 3;
  const int m0 = blockIdx.x * 256, n0 = blockIdx.y * 192;  // R9 plain mapping

  // staging source offsets (inverse-swizzled global address; LDS dest linear)
  int aoff[4], adst[4];
#pragma unroll
  for (int u = 0; u < 4; ++u) {
    int s = u * 512 + tid, row = s >> 3;
    aoff[u] = (m0 + row) * 1024 + (((s & 7) ^ (row & 7)) * 8);
    adst[u] = s * 8;
  }
  int boff[3], bdst[3];
#pragma unroll
  for (int u = 0; u < 3; ++u) {
    int s = u * 512 + tid, row = s >> 3;
    boff[u] = (n0 + row) * 1024 + (((s & 7) ^ (row & 7)) * 8);
    bdst[u] = s * 8;
  }

  const unsigned short* A0 = lds;
  const unsigned short* B0 = lds + 16384;
  const unsigned short* A1 = lds + 28672;
  const unsigned short* B1 = lds + 45056;

  f32x4 acc[8][3];
#pragma unroll
  for (int i = 0; i < 8; ++i)
#pragma unroll
    for (int j = 0; j < 3; ++j) acc[i][j] = (f32x4){0.f, 0.f, 0.f, 0.f};
  bf16x8 ar[4][2], br[3][2];

  // prologue: tile0 full -> buf0 (7 loads); tile1 B -> buf1 (3 loads)
  SA_(0, 0, 0); SA_(0, 0, 1); SA_(0, 0, 2); SA_(0, 0, 3);
  SB_(0, 0, 0); SB_(0, 0, 1); SB_(0, 0, 2);
  SB_(1, 1, 0); SB_(1, 1, 1); SB_(1, 1, 2);
  asm volatile("s_waitcnt vmcnt(3)" ::: "memory");  // tile0 landed; tile1-B in flight
  QKV_BAR();

  // 16 K-tiles of 64; iteration i computes tiles 2i (buf0) and 2i+1 (buf1).
  // Staging map (1 half-tile/phase): ph0/1 A(2i+1)->buf1, ph2/3 B(2i+2)->buf0,
  // ph4/5 A(2i+2)->buf0, ph6/7 B(2i+3)->buf1. Counted waits at end of ph3/ph7.
#pragma unroll 1
  for (int i = 0; i < 8; ++i) {
    const int tn = 2 * i + 2;
    const bool st = (i < 7);
    // ph0: buf0 (mh0,c0)
    qkv_ds_a<0, 0>(A0, wm, quad, l15, ar);
    qkv_ds_b<0>(B0, wn, quad, l15, br);
    SA_(1, 2 * i + 1, 0); SA_(1, 2 * i + 1, 1);
    QKV_BAR(); QKV_LGKM0();
    __builtin_amdgcn_s_setprio(1); qkv_mf<0, 0>(ar, br, acc); __builtin_amdgcn_s_setprio(0);
    QKV_BAR();
    // ph1: buf0 (mh0,c1)
    qkv_ds_a<0, 1>(A0, wm, quad, l15, ar);
    qkv_ds_b<1>(B0, wn, quad, l15, br);
    SA_(1, 2 * i + 1, 2); SA_(1, 2 * i + 1, 3);
    QKV_BAR(); QKV_LGKM0();
    __builtin_amdgcn_s_setprio(1); qkv_mf<0, 1>(ar, br, acc); __builtin_amdgcn_s_setprio(0);
    QKV_BAR();
    // ph2: buf0 (mh1,c0); B(buf0) free (reads done ph1)
    qkv_ds_a<1, 0>(A0, wm, quad, l15, ar);
    if (st) { SB_(0, tn, 0); SB_(0, tn, 1); }
    QKV_BAR(); QKV_LGKM0();
    __builtin_amdgcn_s_setprio(1); qkv_mf<1, 0>(ar, br, acc); __builtin_amdgcn_s_setprio(0);
    QKV_BAR();
    // ph3: buf0 (mh1,c1); counted wait: tile 2i+1 (buf1) must be landed past here
    qkv_ds_a<1, 1>(A0, wm, quad, l15, ar);
    if (st) SB_(0, tn, 2);
    QKV_BAR(); QKV_LGKM0();
    __builtin_amdgcn_s_setprio(1); qkv_mf<1, 1>(ar, br, acc); __builtin_amdgcn_s_setprio(0);
    if (st) asm volatile("s_waitcnt vmcnt(3)" ::: "memory");  // leaves ph2/3 B in flight
    else    asm volatile("s_waitcnt vmcnt(0)" ::: "memory");  // last iter: drain all
    QKV_BAR();
    // ph4: buf1 (mh0,c0); A(buf0) free (reads done ph3)
    qkv_ds_a<0, 0>(A1, wm, quad, l15, ar);
    qkv_ds_b<0>(B1, wn, quad, l15, br);
    if (st) { SA_(0, tn, 0); SA_(0, tn, 1); }
    QKV_BAR(); QKV_LGKM0();
    __builtin_amdgcn_s_setprio(1); qkv_mf<0, 0>(ar, br, acc); __builtin_amdgcn_s_setprio(0);
    QKV_BAR();
    // ph5: buf1 (mh0,c1)
    qkv_ds_a<0, 1>(A1, wm, quad, l15, ar);
    qkv_ds_b<1>(B1, wn, quad, l15, br);
    if (st) { SA_(0, tn, 2); SA_(0, tn, 3); }
    QKV_BAR(); QKV_LGKM0();
    __builtin_amdgcn_s_setprio(1); qkv_mf<0, 1>(ar, br, acc); __builtin_amdgcn_s_setprio(0);
    QKV_BAR();
    // ph6: buf1 (mh1,c0); B(buf1) free (reads done ph5)
    qkv_ds_a<1, 0>(A1, wm, quad, l15, ar);
    if (st) { SB_(1, tn + 1, 0); SB_(1, tn + 1, 1); }
    QKV_BAR(); QKV_LGKM0();
    __builtin_amdgcn_s_setprio(1); qkv_mf<1, 0>(ar, br, acc); __builtin_amdgcn_s_setprio(0);
    QKV_BAR();
    // ph7: buf1 (mh1,c1); counted wait: tile 2i+2 (buf0) landed past here
    qkv_ds_a<1, 1>(A1, wm, quad, l15, ar);
    if (st) SB_(1, tn + 1, 2);
    QKV_BAR(); QKV_LGKM0();
    __builtin_amdgcn_s_setprio(1); qkv_mf<1, 1>(ar, br, acc); __builtin_amdgcn_s_setprio(0);
    asm volatile("s_waitcnt vmcnt(3)" ::: "memory");  // leaves ph6/7 B in flight
    QKV_BAR();
  }

  // epilogue: C[row = m0+wm*128+mi*16+quad*4+r][col = n0+wn*48+nj*16+l15]
#pragma unroll
  for (int nj = 0; nj < 3; ++nj) {
    const int n_abs = n0 + wn * 48 + nj * 16 + l15;  // 0..3071
    const int type = n_abs >> 10;                    // 0=Q 1=K 2=V
    const int n_in = n_abs & 1023;
    const int h = n_in >> 6, kh = n_in & 63;
    const float bv = ((type == 0) ? bQ : (type == 1) ? bK : bV)[n_in];
#pragma unroll
    for (int mi = 0; mi < 8; ++mi) {
      const int mb = m0 + wm * 128 + mi * 16 + quad * 4;
      const int b = mb >> 11, tb = mb & 2047;
      if (type == 2) {
        uint2 pk;
        pk.x = (unsigned)f2bf(acc[mi][nj][0] + bv) |
               ((unsigned)f2bf(acc[mi][nj][1] + bv) << 16);
        pk.y = (unsigned)f2bf(acc[mi][nj][2] + bv) |
               ((unsigned)f2bf(acc[mi][nj][3] + bv) << 16);
        *(uint2*)(Vpg + ((size_t)(b * 16 + h) * 64 + kh) * 1024 + (tb >> 1)) = pk;
      } else {
        unsigned short* dst =
            ((type == 0) ? Qg : Kg) + ((size_t)(b * 16 + h) * 2048 + tb) * 64 + kh;
        // Q pre-scaled by 1/sqrt(Dh) * log2(e) so flash uses exp2 directly
        const float sc = (type == 0) ? 0.18033688011112042f : 1.0f;
        dst[0]   = f2bf((acc[mi][nj][0] + bv) * sc);
        dst[64]  = f2bf((acc[mi][nj][1] + bv) * sc);
        dst[128] = f2bf((acc[mi][nj][2] + bv) * sc);
        dst[192] = f2bf((acc[mi][nj][3] + bv) * sc);
      }
    }
  }
}

#undef SA_
#undef SB_
#undef QKV_BAR
#undef QKV_LGKM0

// ---------------- flash attention (R12: KVBLK=128, 16 barrier periods) ------
// buf b (ushort idx): K at b*16384 (128 rows x 64), V at b*16384+8192
// (64 d-rows x 128 k-ushorts). K chunk swizzle: rho(row) on 8 chunks/row.
// V chunk swizzle: g = p ^ (row&15) on 16 chunks/row (<=4-way aliasing).
__device__ __forceinline__ void stage_kv(const unsigned short* __restrict__ Kb,
                                         const unsigned int* __restrict__ Vb,
                                         unsigned short* smem, int tid, int s0, int b) {
#pragma unroll
  for (int u = 0; u < 4; ++u) {
    int s = u * 256 + tid, row = s >> 3, g = (s & 7) ^ rho(row);
    gl_lds16(Kb + (size_t)(s0 + row) * 64 + g * 8, smem + b * 16384 + s * 8);
  }
#pragma unroll
  for (int u = 0; u < 4; ++u) {
    int s = u * 256 + tid, row = s >> 4, g = (s & 15) ^ (row & 15);
    gl_lds16(Vb + (size_t)row * 1024 + (s0 >> 1) + g * 4,
             smem + b * 16384 + 8192 + s * 8);
  }
}

// block: 256 q-rows of one (b,h); wave owns 64 q; k-tiles of 128, dbuffered.
// grid (bh=64, qt=8): all q-tiles of one bh on one XCD -> K/V L2-local.
__global__ __launch_bounds__(256, 2) void flash_attn(
    const unsigned short* __restrict__ Qg, const unsigned short* __restrict__ Kg,
    const unsigned int* __restrict__ Vpg, unsigned short* __restrict__ OH) {
  __shared__ unsigned short smem[32768];  // 64KB: [K0 16K][V0 16K][K1 16K][V1 16K]
  const int tid = threadIdx.x, lane = tid & 63, w = tid >> 6;
  const int quad = lane >> 4, l15 = lane & 15;
  const int bh = blockIdx.x, qt = blockIdx.y;

  const unsigned short* Qb = Qg + ((size_t)bh * 2048 + qt * 256) * 64;
  const unsigned short* Kb = Kg + (size_t)bh * 2048 * 64;
  const unsigned int*  Vb = Vpg + (size_t)bh * 64 * 1024;

  // stage Q (256 rows = 32KB, into first half of smem) — dead before tile 0
#pragma unroll
  for (int u = 0; u < 8; ++u) {
    int s = u * 256 + tid, row = s >> 3;
    gl_lds16(Qb + row * 64 + ((s & 7) ^ (row & 7)) * 8, smem + s * 8);
  }
  __syncthreads();

  bf16x8 qf[4][2];  // B-operand Q frags, hoisted for whole kernel
#pragma unroll
  for (int qi = 0; qi < 4; ++qi) {
    int row = w * 64 + qi * 16 + l15;
#pragma unroll
    for (int c = 0; c < 2; ++c)
      qf[qi][c] = *(const bf16x8*)(smem + row * 64 + (((c * 4 + quad) ^ (row & 7)) * 8));
  }
  __syncthreads();  // all waves done reading Q; safe to overwrite with K0/V0

  stage_kv(Kb, Vb, smem, tid, 0, 0);

  f32x4 o[4][4];
  float l_part[4] = {0.f, 0.f, 0.f, 0.f};
#pragma unroll
  for (int qi = 0; qi < 4; ++qi)
#pragma unroll
    for (int nj = 0; nj < 4; ++nj) o[qi][nj] = (f32x4){0.f, 0.f, 0.f, 0.f};

  for (int t = 0; t < 16; ++t) {
    __syncthreads();  // drains tile-t staging
    if (t < 15) stage_kv(Kb, Vb, smem, tid, (t + 1) * 128, (t + 1) & 1);
    const unsigned short* Kd = smem + (t & 1) * 16384;
    const unsigned short* Vd = Kd + 8192;

#pragma unroll
    for (int blk = 0; blk < 4; ++blk) {
      // V B-frags: V[d = nj*16+l15][s = blk*32 + quad*8 .. +7] — one b128 each
      bf16x8 vb[4];
#pragma unroll
      for (int nj = 0; nj < 4; ++nj) {
        int vrow = nj * 16 + l15;
        vb[nj] = *(const bf16x8*)(Vd + vrow * 128 +
                                  (((blk * 4 + quad) ^ (vrow & 15)) * 8));
      }
      union { unsigned u[4]; bf16x8 v; } pa[4];
#pragma unroll
      for (int v = 0; v < 2; ++v) {
        // permuted K rows: C/D row m maps to s = blk*32 + 8*quad + 4*v + reg
        int krow = blk * 32 + 8 * (l15 >> 2) + 4 * v + (l15 & 3);
        const unsigned short* kr = Kd + krow * 64;
        bf16x8 ka0 = *(const bf16x8*)(kr + ((quad ^ rho(krow)) * 8));
        bf16x8 ka1 = *(const bf16x8*)(kr + (((4 + quad) ^ rho(krow)) * 8));
#pragma unroll
        for (int qi = 0; qi < 4; ++qi) {
          f32x4 S = (f32x4){0.f, 0.f, 0.f, 0.f};
          S = MFMA32(ka0, qf[qi][0], S, 0, 0, 0);
          S = MFMA32(ka1, qf[qi][1], S, 0, 0, 0);
          float e0 = EXP2(S[0]), e1 = EXP2(S[1]), e2 = EXP2(S[2]), e3 = EXP2(S[3]);
          l_part[qi] += (e0 + e1) + (e2 + e3);
          pa[qi].u[2 * v] = packbf2(e0, e1);
          pa[qi].u[2 * v + 1] = packbf2(e2, e3);
        }
      }
      __builtin_amdgcn_s_setprio(1);
#pragma unroll
      for (int nj = 0; nj < 4; ++nj)
#pragma unroll
        for (int qi = 0; qi < 4; ++qi)
          o[qi][nj] = MFMA32(pa[qi].v, vb[nj], o[qi][nj], 0, 0, 0);
      __builtin_amdgcn_s_setprio(0);
    }
  }

  // l: cross-quad reduce once; normalize + store
  const int b = bh >> 4, h = bh & 15;
#pragma unroll
  for (int qi = 0; qi < 4; ++qi) {
    float l = l_part[qi];
    l += __shfl_xor(l, 16);
    l += __shfl_xor(l, 32);
    float linv = 1.0f / l;
#pragma unroll
    for (int r = 0; r < 4; ++r) {
      float lr = __shfl(linv, 4 * quad + r);  // l of q_local = 4*quad + r
      int trow = qt * 256 + w * 64 + qi * 16 + 4 * quad + r;
#pragma unroll
      for (int nj = 0; nj < 4; ++nj) {
        int col = h * 64 + nj * 16 + l15;
        OH[((size_t)b * 2048 + trow) * 1024 + col] = f2bf(o[qi][nj][r] * lr);
      }
    }
  }
}

// ---------------- output projection (128x128 tile) ----------------
__global__ __launch_bounds__(256) void gemm_o(
    const unsigned short* __restrict__ OHm, const unsigned short* __restrict__ Wot,
    const float* __restrict__ bO, float* __restrict__ Out) {
  __shared__ unsigned short As[128 * 64];  // 16KB
  __shared__ unsigned short Bs[128 * 64];  // 16KB
  const int tid = threadIdx.x, lane = tid & 63, w = tid >> 6;
  const int quad = lane >> 4, l15 = lane & 15;
  const int wm = w & 1, wn = w >> 1;
  // XCD-chunk swizzle (bijective, 512 blocks = 8 XCD x 64): 8 bx x 8 by chunk
  // -> ~2MB A + ~2MB B working set per XCD (L2-fit).
  const int lin = blockIdx.y * 64 + blockIdx.x;
  const int xq = lin & 7, xc = lin >> 3;
  const int m0 = (xq * 8 + (xc & 7)) * 128, n0 = (xc >> 3) * 128;
  f32x4 acc[4][4];
#pragma unroll
  for (int i = 0; i < 4; ++i)
#pragma unroll
    for (int j = 0; j < 4; ++j) acc[i][j] = (f32x4){0.f, 0.f, 0.f, 0.f};

  gemm_mainloop_1024(OHm, Wot, As, Bs, m0, n0, acc);

#pragma unroll
  for (int nj = 0; nj < 4; ++nj) {
    const int n = n0 + wn * 64 + nj * 16 + l15;
    const float bv = bO[n];
#pragma unroll
    for (int mi = 0; mi < 4; ++mi) {
      const int mb = m0 + wm * 64 + mi * 16 + quad * 4;
#pragma unroll
      for (int r = 0; r < 4; ++r)
        Out[(size_t)(mb + r) * 1024 + n] = acc[mi][nj][r] + bv;
    }
  }
}

// ---------------- launch ----------------
extern "C" void kernel_launch(void* const* d_in, const int* in_sizes, int n_in,
                              void* d_out, int out_size, void* d_ws, size_t ws_size,
                              hipStream_t stream) {
  const float* x  = (const float*)d_in[0];
  const float* WQ = (const float*)d_in[1];
  const float* bQ = (const float*)d_in[2];
  const float* WK = (const float*)d_in[3];
  const float* bK = (const float*)d_in[4];
  const float* WV = (const float*)d_in[5];
  const float* bV = (const float*)d_in[6];
  const float* WO = (const float*)d_in[7];
  const float* bO = (const float*)d_in[8];
  float* out = (float*)d_out;

  char* ws = (char*)d_ws;
  unsigned short* Xb   = (unsigned short*)(ws);                // 16 MB
  unsigned short* OH   = (unsigned short*)(ws);                // alias (Xb dead)
  unsigned short* Wqkv = (unsigned short*)(ws + 16777216);     // 6 MB
  unsigned short* Wot  = (unsigned short*)(ws + 23068672);     // 2 MB
  unsigned short* Qg   = (unsigned short*)(ws + 25165824);     // 16 MB
  unsigned short* Kg   = (unsigned short*)(ws + 41943040);     // 16 MB
  unsigned int*   Vpg  = (unsigned int*)  (ws + 58720256);     // 16 MB

  prep_all<<<6144, 256, 0, stream>>>(x, WQ, WK, WV, WO, Xb, Wqkv, Wot);

  dim3 g1(32, 16);
  gemm_qkv<<<g1, 512, 0, stream>>>(Xb, Wqkv, bQ, bK, bV, Qg, Kg, Vpg);
  dim3 g2(64, 8);
  flash_attn<<<g2, 256, 0, stream>>>(Qg, Kg, Vpg, OH);
  dim3 g3(64, 8);
  gemm_o<<<g3, 256, 0, stream>>>(OH, Wot, bO, out);
}

// Round 6
// 268.893 us; speedup vs baseline: 1.0531x; 1.0531x over previous
//
#include <hip/hip_runtime.h>
#include <stdint.h>

// Attention fwd: B=4 T=2048 D=1024 H=16 Dh=64.
// R14 = R13 with the gemm_qkv staging race FIXED: B fragments for both
//   K-chunks are register-cached in ph0/ph1 (br[4][2], R9 layout) so ph2/ph3
//   do NOT re-read B0 from LDS while staging overwrites it. R13's single-C
//   br[4] re-read raced with SB_ writes -> absmax 1.2e-3.
// gemm_qkv: 256x256 8-phase (per-wave 128x64, acc[8][4], BK=64, 128KB LDS
//   dbuf, counted vmcnt(4) at ph3/ph7, grid 32x12). flash: R9 form.
// gemm_o: R9 128x64/1024-block form.

typedef __attribute__((ext_vector_type(8))) short bf16x8;
typedef __attribute__((ext_vector_type(4))) float f32x4;

#define MFMA32 __builtin_amdgcn_mfma_f32_16x16x32_bf16

#if __has_builtin(__builtin_amdgcn_exp2f)
#define EXP2(x) __builtin_amdgcn_exp2f(x)
#else
#define EXP2(x) exp2f(x)   // host pass only
#endif

__device__ __forceinline__ unsigned short f2bf(float f) {
  union { float f; unsigned int u; } v; v.f = f;
  unsigned int r = v.u + 0x7FFFu + ((v.u >> 16) & 1u);  // RNE
  return (unsigned short)(r >> 16);
}

__device__ __forceinline__ void gl_lds16(const void* g, void* l) {
  __builtin_amdgcn_global_load_lds(
      (const __attribute__((address_space(1))) unsigned int*)g,
      (__attribute__((address_space(3))) unsigned int*)l, 16, 0, 0);
}

// truncating pack of two positive fp32 -> one u32 (two bf16)
__device__ __forceinline__ unsigned packbf2(float lo, float hi) {
  union { float f; unsigned u; } a, b; a.f = lo; b.f = hi;
  return __builtin_amdgcn_perm(b.u, a.u, 0x07060302u);
}

// LDS chunk swizzle for K/V tiles (conflict-free for permuted-row b128 reads)
__device__ __forceinline__ int rho(int r) { return (r & 3) | ((r >> 1) & 4); }

// ---------------- merged prep kernel ----------------
__device__ __forceinline__ void conv8(const float* __restrict__ src,
                                      unsigned short* __restrict__ dst, int i) {
  const float4* sp = (const float4*)src;
  float4 a = sp[2 * i], b = sp[2 * i + 1];
  union { unsigned short u[8]; uint4 v; } o;
  o.u[0] = f2bf(a.x); o.u[1] = f2bf(a.y); o.u[2] = f2bf(a.z); o.u[3] = f2bf(a.w);
  o.u[4] = f2bf(b.x); o.u[5] = f2bf(b.y); o.u[6] = f2bf(b.z); o.u[7] = f2bf(b.w);
  ((uint4*)dst)[i] = o.v;
}

__global__ __launch_bounds__(256) void prep_all(
    const float* __restrict__ x, const float* __restrict__ WQ,
    const float* __restrict__ WK, const float* __restrict__ WV,
    const float* __restrict__ WO, unsigned short* __restrict__ Xb,
    unsigned short* __restrict__ Wqkv, unsigned short* __restrict__ Wot) {
  const int bx = blockIdx.x, t = threadIdx.x;
  if (bx < 4096) {
    conv8(x, Xb, bx * 256 + t);
  } else if (bx < 4608) {
    conv8(WQ, Wqkv, (bx - 4096) * 256 + t);
  } else if (bx < 5120) {
    conv8(WK, Wqkv + 1048576, (bx - 4608) * 256 + t);
  } else if (bx < 5632) {
    conv8(WV, Wqkv + 2097152, (bx - 5120) * 256 + t);
  } else {
    // W_O [16][1024][64] fp32 -> Wot [d][h*64+k] bf16
    int tid = (bx - 5632) * 256 + t;
    int h = tid >> 13, rem = tid & 8191;
    int d = rem >> 3, c = rem & 7;
    const float4* sp = (const float4*)(WO + (size_t)h * 65536 + d * 64 + c * 8);
    float4 a = sp[0], e = sp[1];
    union { unsigned short u[8]; uint4 v; } o;
    o.u[0] = f2bf(a.x); o.u[1] = f2bf(a.y); o.u[2] = f2bf(a.z); o.u[3] = f2bf(a.w);
    o.u[4] = f2bf(e.x); o.u[5] = f2bf(e.y); o.u[6] = f2bf(e.z); o.u[7] = f2bf(e.w);
    *(uint4*)(Wot + (size_t)d * 1024 + h * 64 + c * 8) = o.v;
  }
}

// ---------------- QKV projection: 256x256 tile, 8-phase pipelined ------------
// LDS ushort layout: A0 @0 (256x64), B0 @16384, A1 @32768, B1 @49152 (32KB ea).
// Swizzle: element (row,k) at row*64 + ((k>>3)^(row&7))*8 + (k&7)  (involution,
// staged via pre-swizzled global source). 8 waves as 2M x 4N: per-wave 128x64.
// REGISTER REUSE CONTRACT (race-free staging): br[nj][C] holds BOTH K-chunks,
// loaded ph0/ph1 (resp ph4/ph5); ph2/ph3 (ph6/ph7) reuse br from registers so
// the B buffer has NO LDS reads after ph1 (ph5) and can be staged ph2/ph3.

template <int MH, int C>
__device__ __forceinline__ void qkv_ds_a(const unsigned short* A, int wm, int quad,
                                         int l15, bf16x8 ar[4][2]) {
#pragma unroll
  for (int ii = 0; ii < 4; ++ii) {
    int ra = wm * 128 + MH * 64 + ii * 16 + l15;
    ar[ii][C] = *(const bf16x8*)(A + ra * 64 + (((C * 4 + quad) ^ (ra & 7)) * 8));
  }
}

template <int C>
__device__ __forceinline__ void qkv_ds_b(const unsigned short* B, int wn, int quad,
                                         int l15, bf16x8 br[4][2]) {
#pragma unroll
  for (int nj = 0; nj < 4; ++nj) {
    int rb = wn * 64 + nj * 16 + l15;
    br[nj][C] = *(const bf16x8*)(B + rb * 64 + (((C * 4 + quad) ^ (rb & 7)) * 8));
  }
}

template <int MH, int C>
__device__ __forceinline__ void qkv_mf(const bf16x8 ar[4][2], const bf16x8 br[4][2],
                                       f32x4 acc[8][4]) {
#pragma unroll
  for (int ii = 0; ii < 4; ++ii)
#pragma unroll
    for (int nj = 0; nj < 4; ++nj)
      acc[MH * 4 + ii][nj] =
          MFMA32(ar[ii][C], br[nj][C], acc[MH * 4 + ii][nj], 0, 0, 0);
}

#define QKV_BAR() __builtin_amdgcn_s_barrier()
#define QKV_LGKM0() asm volatile("s_waitcnt lgkmcnt(0)" ::: "memory")
#define SA_(bb, kt, u) \
  gl_lds16(Xb + (size_t)aoff[u] + (size_t)(kt) * 64, lds + (bb)*32768 + adst[u])
#define SB_(bb, kt, u) \
  gl_lds16(Wqkv + (size_t)boff[u] + (size_t)(kt) * 64, lds + (bb)*32768 + 16384 + bdst[u])

__global__ __launch_bounds__(512, 2) void gemm_qkv(
    const unsigned short* __restrict__ Xb, const unsigned short* __restrict__ Wqkv,
    const float* __restrict__ bQ, const float* __restrict__ bK,
    const float* __restrict__ bV, unsigned short* __restrict__ Qg,
    unsigned short* __restrict__ Kg, unsigned int* __restrict__ Vpg) {
  __shared__ unsigned short lds[65536];  // 128 KB
  const int tid = threadIdx.x, lane = tid & 63, w = tid >> 6;
  const int quad = lane >> 4, l15 = lane & 15;
  const int wm = w >> 2, wn = w & 3;
  const int m0 = blockIdx.x * 256, n0 = blockIdx.y * 256;

  // staging source offsets (inverse-swizzled global address; LDS dest linear)
  int aoff[4], adst[4], boff[4], bdst[4];
#pragma unroll
  for (int u = 0; u < 4; ++u) {
    int s = u * 512 + tid, row = s >> 3;
    int cl = ((s & 7) ^ (row & 7)) * 8;
    aoff[u] = (m0 + row) * 1024 + cl;
    boff[u] = (n0 + row) * 1024 + cl;
    adst[u] = s * 8;
    bdst[u] = s * 8;
  }

  const unsigned short* A0 = lds;
  const unsigned short* B0 = lds + 16384;
  const unsigned short* A1 = lds + 32768;
  const unsigned short* B1 = lds + 49152;

  f32x4 acc[8][4];
#pragma unroll
  for (int i = 0; i < 8; ++i)
#pragma unroll
    for (int j = 0; j < 4; ++j) acc[i][j] = (f32x4){0.f, 0.f, 0.f, 0.f};
  bf16x8 ar[4][2], br[4][2];

  // prologue: tile0 full -> buf0 (8 loads); tile1 B -> buf1 (4 loads)
  SA_(0, 0, 0); SA_(0, 0, 1); SA_(0, 0, 2); SA_(0, 0, 3);
  SB_(0, 0, 0); SB_(0, 0, 1); SB_(0, 0, 2); SB_(0, 0, 3);
  SB_(1, 1, 0); SB_(1, 1, 1); SB_(1, 1, 2); SB_(1, 1, 3);
  asm volatile("s_waitcnt vmcnt(4)" ::: "memory");  // tile0 landed; tile1-B in flight
  QKV_BAR();

  // 16 K-tiles of 64; iteration i computes tiles 2i (buf0) and 2i+1 (buf1).
  // Staging (2 loads/phase): ph0/1 A(2i+1)->buf1, ph2/3 B(2i+2)->buf0,
  // ph4/5 A(2i+2)->buf0, ph6/7 B(2i+3)->buf1.
  // vmcnt ledger at ph3-wait: [B1:4][A1:4][B0new:4] -> vmcnt(4) drains A1+B1
  // (read ph4-7); at ph7-wait: [B0n:4][A0n:4][B1n:4] -> vmcnt(4) drains
  // A0n+B0n (read next ph0). Prologue vmcnt(4) drains tile0's 8.
#pragma unroll 1
  for (int i = 0; i < 8; ++i) {
    const int tn = 2 * i + 2;
    const bool st = (i < 7);
    // ph0: buf0 (mh0,c0); loads br[.][0]
    qkv_ds_a<0, 0>(A0, wm, quad, l15, ar);
    qkv_ds_b<0>(B0, wn, quad, l15, br);
    SA_(1, 2 * i + 1, 0); SA_(1, 2 * i + 1, 1);
    QKV_BAR(); QKV_LGKM0();
    __builtin_amdgcn_s_setprio(1); qkv_mf<0, 0>(ar, br, acc); __builtin_amdgcn_s_setprio(0);
    QKV_BAR();
    // ph1: buf0 (mh0,c1); loads br[.][1] — last LDS reads of B0
    qkv_ds_a<0, 1>(A0, wm, quad, l15, ar);
    qkv_ds_b<1>(B0, wn, quad, l15, br);
    SA_(1, 2 * i + 1, 2); SA_(1, 2 * i + 1, 3);
    QKV_BAR(); QKV_LGKM0();
    __builtin_amdgcn_s_setprio(1); qkv_mf<0, 1>(ar, br, acc); __builtin_amdgcn_s_setprio(0);
    QKV_BAR();
    // ph2: buf0 (mh1,c0); br reused from regs; B0 free -> stage into it
    qkv_ds_a<1, 0>(A0, wm, quad, l15, ar);
    if (st) { SB_(0, tn, 0); SB_(0, tn, 1); }
    QKV_BAR(); QKV_LGKM0();
    __builtin_amdgcn_s_setprio(1); qkv_mf<1, 0>(ar, br, acc); __builtin_amdgcn_s_setprio(0);
    QKV_BAR();
    // ph3: buf0 (mh1,c1); counted wait
    qkv_ds_a<1, 1>(A0, wm, quad, l15, ar);
    if (st) { SB_(0, tn, 2); SB_(0, tn, 3); }
    QKV_BAR(); QKV_LGKM0();
    __builtin_amdgcn_s_setprio(1); qkv_mf<1, 1>(ar, br, acc); __builtin_amdgcn_s_setprio(0);
    if (st) asm volatile("s_waitcnt vmcnt(4)" ::: "memory");
    else    asm volatile("s_waitcnt vmcnt(0)" ::: "memory");  // last iter: drain all
    QKV_BAR();
    // ph4: buf1 (mh0,c0); A(buf0) free (reads done ph3)
    qkv_ds_a<0, 0>(A1, wm, quad, l15, ar);
    qkv_ds_b<0>(B1, wn, quad, l15, br);
    if (st) { SA_(0, tn, 0); SA_(0, tn, 1); }
    QKV_BAR(); QKV_LGKM0();
    __builtin_amdgcn_s_setprio(1); qkv_mf<0, 0>(ar, br, acc); __builtin_amdgcn_s_setprio(0);
    QKV_BAR();
    // ph5: buf1 (mh0,c1) — last LDS reads of B1
    qkv_ds_a<0, 1>(A1, wm, quad, l15, ar);
    qkv_ds_b<1>(B1, wn, quad, l15, br);
    if (st) { SA_(0, tn, 2); SA_(0, tn, 3); }
    QKV_BAR(); QKV_LGKM0();
    __builtin_amdgcn_s_setprio(1); qkv_mf<0, 1>(ar, br, acc); __builtin_amdgcn_s_setprio(0);
    QKV_BAR();
    // ph6: buf1 (mh1,c0); br reused; B1 free -> stage into it
    qkv_ds_a<1, 0>(A1, wm, quad, l15, ar);
    if (st) { SB_(1, tn + 1, 0); SB_(1, tn + 1, 1); }
    QKV_BAR(); QKV_LGKM0();
    __builtin_amdgcn_s_setprio(1); qkv_mf<1, 0>(ar, br, acc); __builtin_amdgcn_s_setprio(0);
    QKV_BAR();
    // ph7: buf1 (mh1,c1); counted wait
    qkv_ds_a<1, 1>(A1, wm, quad, l15, ar);
    if (st) { SB_(1, tn + 1, 2); SB_(1, tn + 1, 3); }
    QKV_BAR(); QKV_LGKM0();
    __builtin_amdgcn_s_setprio(1); qkv_mf<1, 1>(ar, br, acc); __builtin_amdgcn_s_setprio(0);
    asm volatile("s_waitcnt vmcnt(4)" ::: "memory");
    QKV_BAR();
  }

  // epilogue: C[row = m0+wm*128+mi*16+quad*4+r][col = n0+wn*64+nj*16+l15]
#pragma unroll
  for (int nj = 0; nj < 4; ++nj) {
    const int n_abs = n0 + wn * 64 + nj * 16 + l15;  // 0..3071
    const int type = n_abs >> 10;                    // 0=Q 1=K 2=V
    const int n_in = n_abs & 1023;
    const int h = n_in >> 6, kh = n_in & 63;
    const float bv = ((type == 0) ? bQ : (type == 1) ? bK : bV)[n_in];
#pragma unroll
    for (int mi = 0; mi < 8; ++mi) {
      const int mb = m0 + wm * 128 + mi * 16 + quad * 4;
      const int b = mb >> 11, tb = mb & 2047;
      if (type == 2) {
        uint2 pk;
        pk.x = (unsigned)f2bf(acc[mi][nj][0] + bv) |
               ((unsigned)f2bf(acc[mi][nj][1] + bv) << 16);
        pk.y = (unsigned)f2bf(acc[mi][nj][2] + bv) |
               ((unsigned)f2bf(acc[mi][nj][3] + bv) << 16);
        *(uint2*)(Vpg + ((size_t)(b * 16 + h) * 64 + kh) * 1024 + (tb >> 1)) = pk;
      } else {
        unsigned short* dst =
            ((type == 0) ? Qg : Kg) + ((size_t)(b * 16 + h) * 2048 + tb) * 64 + kh;
        // Q pre-scaled by 1/sqrt(Dh) * log2(e) so flash uses exp2 directly
        const float sc = (type == 0) ? 0.18033688011112042f : 1.0f;
        dst[0]   = f2bf((acc[mi][nj][0] + bv) * sc);
        dst[64]  = f2bf((acc[mi][nj][1] + bv) * sc);
        dst[128] = f2bf((acc[mi][nj][2] + bv) * sc);
        dst[192] = f2bf((acc[mi][nj][3] + bv) * sc);
      }
    }
  }
}

#undef SA_
#undef SB_
#undef QKV_BAR
#undef QKV_LGKM0

// ---------------- flash attention (R9 form: 256 thr, 4 waves x 64 q) --------
__device__ __forceinline__ void stage_kv(const unsigned short* __restrict__ Kb,
                                         const unsigned int* __restrict__ Vb,
                                         unsigned short* smem, int tid, int s0, int b) {
#pragma unroll
  for (int u = 0; u < 2; ++u) {
    int s = u * 256 + tid, row = s >> 3, g = (s & 7) ^ rho(row);
    gl_lds16(Kb + (size_t)(s0 + row) * 64 + g * 8, smem + b * 8192 + s * 8);
    gl_lds16(Vb + (size_t)row * 1024 + (s0 >> 1) + g * 4,
             smem + b * 8192 + 4096 + s * 8);
  }
}

// block: 256 q-rows of one (b,h); wave owns 64 q; k-tiles of 64, double-buffered.
// grid (bh=64, qt=8): all q-tiles of one bh on one XCD -> K/V L2-local.
__global__ __launch_bounds__(256, 2) void flash_attn(
    const unsigned short* __restrict__ Qg, const unsigned short* __restrict__ Kg,
    const unsigned int* __restrict__ Vpg, unsigned short* __restrict__ OH) {
  __shared__ unsigned short smem[16384];  // 32KB: [K0 8K][V0 8K][K1 8K][V1 8K]
  const int tid = threadIdx.x, lane = tid & 63, w = tid >> 6;
  const int quad = lane >> 4, l15 = lane & 15;
  const int bh = blockIdx.x, qt = blockIdx.y;

  const unsigned short* Qb = Qg + ((size_t)bh * 2048 + qt * 256) * 64;
  const unsigned short* Kb = Kg + (size_t)bh * 2048 * 64;
  const unsigned int*  Vb = Vpg + (size_t)bh * 64 * 1024;

  // stage Q (256 rows = 32KB, whole smem) — dead before tile 0
#pragma unroll
  for (int u = 0; u < 8; ++u) {
    int s = u * 256 + tid, row = s >> 3;
    gl_lds16(Qb + row * 64 + ((s & 7) ^ (row & 7)) * 8, smem + s * 8);
  }
  __syncthreads();

  bf16x8 qf[4][2];  // B-operand Q frags, hoisted for whole kernel
#pragma unroll
  for (int qi = 0; qi < 4; ++qi) {
    int row = w * 64 + qi * 16 + l15;
#pragma unroll
    for (int c = 0; c < 2; ++c)
      qf[qi][c] = *(const bf16x8*)(smem + row * 64 + (((c * 4 + quad) ^ (row & 7)) * 8));
  }
  __syncthreads();  // all waves done reading Q; safe to overwrite with K0/V0

  stage_kv(Kb, Vb, smem, tid, 0, 0);

  f32x4 o[4][4];
  float l_part[4] = {0.f, 0.f, 0.f, 0.f};
#pragma unroll
  for (int qi = 0; qi < 4; ++qi)
#pragma unroll
    for (int nj = 0; nj < 4; ++nj) o[qi][nj] = (f32x4){0.f, 0.f, 0.f, 0.f};

  for (int t = 0; t < 32; ++t) {
    __syncthreads();  // drains tile-t staging
    if (t < 31) stage_kv(Kb, Vb, smem, tid, (t + 1) * 64, (t + 1) & 1);
    const unsigned short* Kd = smem + (t & 1) * 8192;
    const unsigned short* Vd = Kd + 4096;

#pragma unroll
    for (int blk = 0; blk < 2; ++blk) {
      // V B-frags: Vt[dh = nj*16+l15][s = blk*32 + quad*8 .. +7] — one b128 each
      bf16x8 vb[4];
#pragma unroll
      for (int nj = 0; nj < 4; ++nj) {
        int vrow = nj * 16 + l15;
        vb[nj] = *(const bf16x8*)(Vd + vrow * 64 + (((blk * 4 + quad) ^ rho(vrow)) * 8));
      }
      union { unsigned u[4]; bf16x8 v; } pa[4];
#pragma unroll
      for (int v = 0; v < 2; ++v) {
        // permuted K rows: C/D row m maps to s = blk*32 + 8*quad + 4*v + reg
        int krow = blk * 32 + 8 * (l15 >> 2) + 4 * v + (l15 & 3);
        const unsigned short* kr = Kd + krow * 64;
        bf16x8 ka0 = *(const bf16x8*)(kr + ((quad ^ rho(krow)) * 8));
        bf16x8 ka1 = *(const bf16x8*)(kr + (((4 + quad) ^ rho(krow)) * 8));
#pragma unroll
        for (int qi = 0; qi < 4; ++qi) {
          f32x4 S = (f32x4){0.f, 0.f, 0.f, 0.f};
          S = MFMA32(ka0, qf[qi][0], S, 0, 0, 0);
          S = MFMA32(ka1, qf[qi][1], S, 0, 0, 0);
          float e0 = EXP2(S[0]), e1 = EXP2(S[1]), e2 = EXP2(S[2]), e3 = EXP2(S[3]);
          l_part[qi] += (e0 + e1) + (e2 + e3);
          pa[qi].u[2 * v] = packbf2(e0, e1);
          pa[qi].u[2 * v + 1] = packbf2(e2, e3);
        }
      }
#pragma unroll
      for (int nj = 0; nj < 4; ++nj)
#pragma unroll
        for (int qi = 0; qi < 4; ++qi)
          o[qi][nj] = MFMA32(pa[qi].v, vb[nj], o[qi][nj], 0, 0, 0);
    }
  }

  // l: cross-quad reduce once; normalize + store
  const int b = bh >> 4, h = bh & 15;
#pragma unroll
  for (int qi = 0; qi < 4; ++qi) {
    float l = l_part[qi];
    l += __shfl_xor(l, 16);
    l += __shfl_xor(l, 32);
    float linv = 1.0f / l;
#pragma unroll
    for (int r = 0; r < 4; ++r) {
      float lr = __shfl(linv, 4 * quad + r);  // l of q_local = 4*quad + r
      int trow = qt * 256 + w * 64 + qi * 16 + 4 * quad + r;
#pragma unroll
      for (int nj = 0; nj < 4; ++nj) {
        int col = h * 64 + nj * 16 + l15;
        OH[((size_t)b * 2048 + trow) * 1024 + col] = f2bf(o[qi][nj][r] * lr);
      }
    }
  }
}

// ---------------- output projection (128x64 tile, R9 form) ----------------
__global__ __launch_bounds__(256) void gemm_o(
    const unsigned short* __restrict__ OHm, const unsigned short* __restrict__ Wot,
    const float* __restrict__ bO, float* __restrict__ Out) {
  __shared__ unsigned short As[128 * 64];  // 16KB
  __shared__ unsigned short Bs[64 * 64];   // 8KB
  const int tid = threadIdx.x, lane = tid & 63, w = tid >> 6;
  const int quad = lane >> 4, l15 = lane & 15;
  const int wm = w & 1, wn = w >> 1;
  const int m0 = blockIdx.x * 128, n0 = blockIdx.y * 64;
  f32x4 acc[4][2];
#pragma unroll
  for (int i = 0; i < 4; ++i)
#pragma unroll
    for (int j = 0; j < 2; ++j) acc[i][j] = (f32x4){0.f, 0.f, 0.f, 0.f};

  for (int k0 = 0; k0 < 1024; k0 += 64) {
    __syncthreads();
#pragma unroll
    for (int u = 0; u < 4; ++u) {
      int s = u * 256 + tid, row = s >> 3;
      int cl = ((s & 7) ^ (row & 7)) * 8;
      gl_lds16(OHm + (size_t)(m0 + row) * 1024 + k0 + cl, As + s * 8);
    }
#pragma unroll
    for (int u = 0; u < 2; ++u) {
      int s = u * 256 + tid, row = s >> 3;
      int cl = ((s & 7) ^ (row & 7)) * 8;
      gl_lds16(Wot + (size_t)(n0 + row) * 1024 + k0 + cl, Bs + s * 8);
    }
    __syncthreads();
    bf16x8 af[4][2], bfr[2][2];
#pragma unroll
    for (int i = 0; i < 4; ++i) {
      int ra = wm * 64 + i * 16 + l15;
#pragma unroll
      for (int c = 0; c < 2; ++c)
        af[i][c] = *(const bf16x8*)(As + ra * 64 + (((c * 4 + quad) ^ (ra & 7)) * 8));
    }
#pragma unroll
    for (int j = 0; j < 2; ++j) {
      int rb = wn * 32 + j * 16 + l15;
#pragma unroll
      for (int c = 0; c < 2; ++c)
        bfr[j][c] = *(const bf16x8*)(Bs + rb * 64 + (((c * 4 + quad) ^ (rb & 7)) * 8));
    }
#pragma unroll
    for (int mi = 0; mi < 4; ++mi)
#pragma unroll
      for (int nj = 0; nj < 2; ++nj) {
        acc[mi][nj] = MFMA32(af[mi][0], bfr[nj][0], acc[mi][nj], 0, 0, 0);
        acc[mi][nj] = MFMA32(af[mi][1], bfr[nj][1], acc[mi][nj], 0, 0, 0);
      }
  }

#pragma unroll
  for (int nj = 0; nj < 2; ++nj) {
    const int n = n0 + wn * 32 + nj * 16 + l15;
    const float bv = bO[n];
#pragma unroll
    for (int mi = 0; mi < 4; ++mi) {
      const int mb = m0 + wm * 64 + mi * 16 + quad * 4;
#pragma unroll
      for (int r = 0; r < 4; ++r)
        Out[(size_t)(mb + r) * 1024 + n] = acc[mi][nj][r] + bv;
    }
  }
}

// ---------------- launch ----------------
extern "C" void kernel_launch(void* const* d_in, const int* in_sizes, int n_in,
                              void* d_out, int out_size, void* d_ws, size_t ws_size,
                              hipStream_t stream) {
  const float* x  = (const float*)d_in[0];
  const float* WQ = (const float*)d_in[1];
  const float* bQ = (const float*)d_in[2];
  const float* WK = (const float*)d_in[3];
  const float* bK = (const float*)d_in[4];
  const float* WV = (const float*)d_in[5];
  const float* bV = (const float*)d_in[6];
  const float* WO = (const float*)d_in[7];
  const float* bO = (const float*)d_in[8];
  float* out = (float*)d_out;

  char* ws = (char*)d_ws;
  unsigned short* Xb   = (unsigned short*)(ws);                // 16 MB
  unsigned short* OH   = (unsigned short*)(ws);                // alias (Xb dead)
  unsigned short* Wqkv = (unsigned short*)(ws + 16777216);     // 6 MB
  unsigned short* Wot  = (unsigned short*)(ws + 23068672);     // 2 MB
  unsigned short* Qg   = (unsigned short*)(ws + 25165824);     // 16 MB
  unsigned short* Kg   = (unsigned short*)(ws + 41943040);     // 16 MB
  unsigned int*   Vpg  = (unsigned int*)  (ws + 58720256);     // 16 MB

  prep_all<<<6144, 256, 0, stream>>>(x, WQ, WK, WV, WO, Xb, Wqkv, Wot);

  dim3 g1(32, 12);
  gemm_qkv<<<g1, 512, 0, stream>>>(Xb, Wqkv, bQ, bK, bV, Qg, Kg, Vpg);
  dim3 g2(64, 8);
  flash_attn<<<g2, 256, 0, stream>>>(Qg, Kg, Vpg, OH);
  dim3 g3(64, 16);
  gemm_o<<<g3, 256, 0, stream>>>(OH, Wot, bO, out);
}

// Round 7
// 262.641 us; speedup vs baseline: 1.0782x; 1.0238x over previous
//
#include <hip/hip_runtime.h>
#include <stdint.h>

// Attention fwd: B=4 T=2048 D=1024 H=16 Dh=64.
// R15 = R14 with ONE change: gemm_qkv __launch_bounds__(512,2) -> (512,1).
//   R14 counters proved acc-spill: VGPR_Count=128 (acc[8][4] alone is 128),
//   WRITE 96.9MB vs 48MB real output (+49MB scratch), MfmaUtil 23.8.
//   The (512,2) bound resolved to a 128-VGPR cap (4 waves/EU target);
//   (512,1) = 1 block/CU (LDS forces that anyway) -> 256 VGPR budget,
//   need ~220. This is m201's occupancy regime (1 blk/CU, 62% MfmaUtil).
// gemm_qkv: 256x256 8-phase, race-free reg-cached B frags (R14 contract).
// flash: R9 form (~73us). gemm_o: R9 128x64/1024-block form.

typedef __attribute__((ext_vector_type(8))) short bf16x8;
typedef __attribute__((ext_vector_type(4))) float f32x4;

#define MFMA32 __builtin_amdgcn_mfma_f32_16x16x32_bf16

#if __has_builtin(__builtin_amdgcn_exp2f)
#define EXP2(x) __builtin_amdgcn_exp2f(x)
#else
#define EXP2(x) exp2f(x)   // host pass only
#endif

__device__ __forceinline__ unsigned short f2bf(float f) {
  union { float f; unsigned int u; } v; v.f = f;
  unsigned int r = v.u + 0x7FFFu + ((v.u >> 16) & 1u);  // RNE
  return (unsigned short)(r >> 16);
}

__device__ __forceinline__ void gl_lds16(const void* g, void* l) {
  __builtin_amdgcn_global_load_lds(
      (const __attribute__((address_space(1))) unsigned int*)g,
      (__attribute__((address_space(3))) unsigned int*)l, 16, 0, 0);
}

// truncating pack of two positive fp32 -> one u32 (two bf16)
__device__ __forceinline__ unsigned packbf2(float lo, float hi) {
  union { float f; unsigned u; } a, b; a.f = lo; b.f = hi;
  return __builtin_amdgcn_perm(b.u, a.u, 0x07060302u);
}

// LDS chunk swizzle for K/V tiles (conflict-free for permuted-row b128 reads)
__device__ __forceinline__ int rho(int r) { return (r & 3) | ((r >> 1) & 4); }

// ---------------- merged prep kernel ----------------
__device__ __forceinline__ void conv8(const float* __restrict__ src,
                                      unsigned short* __restrict__ dst, int i) {
  const float4* sp = (const float4*)src;
  float4 a = sp[2 * i], b = sp[2 * i + 1];
  union { unsigned short u[8]; uint4 v; } o;
  o.u[0] = f2bf(a.x); o.u[1] = f2bf(a.y); o.u[2] = f2bf(a.z); o.u[3] = f2bf(a.w);
  o.u[4] = f2bf(b.x); o.u[5] = f2bf(b.y); o.u[6] = f2bf(b.z); o.u[7] = f2bf(b.w);
  ((uint4*)dst)[i] = o.v;
}

__global__ __launch_bounds__(256) void prep_all(
    const float* __restrict__ x, const float* __restrict__ WQ,
    const float* __restrict__ WK, const float* __restrict__ WV,
    const float* __restrict__ WO, unsigned short* __restrict__ Xb,
    unsigned short* __restrict__ Wqkv, unsigned short* __restrict__ Wot) {
  const int bx = blockIdx.x, t = threadIdx.x;
  if (bx < 4096) {
    conv8(x, Xb, bx * 256 + t);
  } else if (bx < 4608) {
    conv8(WQ, Wqkv, (bx - 4096) * 256 + t);
  } else if (bx < 5120) {
    conv8(WK, Wqkv + 1048576, (bx - 4608) * 256 + t);
  } else if (bx < 5632) {
    conv8(WV, Wqkv + 2097152, (bx - 5120) * 256 + t);
  } else {
    // W_O [16][1024][64] fp32 -> Wot [d][h*64+k] bf16
    int tid = (bx - 5632) * 256 + t;
    int h = tid >> 13, rem = tid & 8191;
    int d = rem >> 3, c = rem & 7;
    const float4* sp = (const float4*)(WO + (size_t)h * 65536 + d * 64 + c * 8);
    float4 a = sp[0], e = sp[1];
    union { unsigned short u[8]; uint4 v; } o;
    o.u[0] = f2bf(a.x); o.u[1] = f2bf(a.y); o.u[2] = f2bf(a.z); o.u[3] = f2bf(a.w);
    o.u[4] = f2bf(e.x); o.u[5] = f2bf(e.y); o.u[6] = f2bf(e.z); o.u[7] = f2bf(e.w);
    *(uint4*)(Wot + (size_t)d * 1024 + h * 64 + c * 8) = o.v;
  }
}

// ---------------- QKV projection: 256x256 tile, 8-phase pipelined ------------
// LDS ushort layout: A0 @0 (256x64), B0 @16384, A1 @32768, B1 @49152 (32KB ea).
// Swizzle: element (row,k) at row*64 + ((k>>3)^(row&7))*8 + (k&7)  (involution,
// staged via pre-swizzled global source). 8 waves as 2M x 4N: per-wave 128x64.
// REGISTER REUSE CONTRACT (race-free staging): br[nj][C] holds BOTH K-chunks,
// loaded ph0/ph1 (resp ph4/ph5); ph2/ph3 (ph6/ph7) reuse br from registers so
// the B buffer has NO LDS reads after ph1 (ph5) and can be staged ph2/ph3.

template <int MH, int C>
__device__ __forceinline__ void qkv_ds_a(const unsigned short* A, int wm, int quad,
                                         int l15, bf16x8 ar[4][2]) {
#pragma unroll
  for (int ii = 0; ii < 4; ++ii) {
    int ra = wm * 128 + MH * 64 + ii * 16 + l15;
    ar[ii][C] = *(const bf16x8*)(A + ra * 64 + (((C * 4 + quad) ^ (ra & 7)) * 8));
  }
}

template <int C>
__device__ __forceinline__ void qkv_ds_b(const unsigned short* B, int wn, int quad,
                                         int l15, bf16x8 br[4][2]) {
#pragma unroll
  for (int nj = 0; nj < 4; ++nj) {
    int rb = wn * 64 + nj * 16 + l15;
    br[nj][C] = *(const bf16x8*)(B + rb * 64 + (((C * 4 + quad) ^ (rb & 7)) * 8));
  }
}

template <int MH, int C>
__device__ __forceinline__ void qkv_mf(const bf16x8 ar[4][2], const bf16x8 br[4][2],
                                       f32x4 acc[8][4]) {
#pragma unroll
  for (int ii = 0; ii < 4; ++ii)
#pragma unroll
    for (int nj = 0; nj < 4; ++nj)
      acc[MH * 4 + ii][nj] =
          MFMA32(ar[ii][C], br[nj][C], acc[MH * 4 + ii][nj], 0, 0, 0);
}

#define QKV_BAR() __builtin_amdgcn_s_barrier()
#define QKV_LGKM0() asm volatile("s_waitcnt lgkmcnt(0)" ::: "memory")
#define SA_(bb, kt, u) \
  gl_lds16(Xb + (size_t)aoff[u] + (size_t)(kt) * 64, lds + (bb)*32768 + adst[u])
#define SB_(bb, kt, u) \
  gl_lds16(Wqkv + (size_t)boff[u] + (size_t)(kt) * 64, lds + (bb)*32768 + 16384 + bdst[u])

__global__ __launch_bounds__(512, 1) void gemm_qkv(
    const unsigned short* __restrict__ Xb, const unsigned short* __restrict__ Wqkv,
    const float* __restrict__ bQ, const float* __restrict__ bK,
    const float* __restrict__ bV, unsigned short* __restrict__ Qg,
    unsigned short* __restrict__ Kg, unsigned int* __restrict__ Vpg) {
  __shared__ unsigned short lds[65536];  // 128 KB
  const int tid = threadIdx.x, lane = tid & 63, w = tid >> 6;
  const int quad = lane >> 4, l15 = lane & 15;
  const int wm = w >> 2, wn = w & 3;
  const int m0 = blockIdx.x * 256, n0 = blockIdx.y * 256;

  // staging source offsets (inverse-swizzled global address; LDS dest linear)
  int aoff[4], adst[4], boff[4], bdst[4];
#pragma unroll
  for (int u = 0; u < 4; ++u) {
    int s = u * 512 + tid, row = s >> 3;
    int cl = ((s & 7) ^ (row & 7)) * 8;
    aoff[u] = (m0 + row) * 1024 + cl;
    boff[u] = (n0 + row) * 1024 + cl;
    adst[u] = s * 8;
    bdst[u] = s * 8;
  }

  const unsigned short* A0 = lds;
  const unsigned short* B0 = lds + 16384;
  const unsigned short* A1 = lds + 32768;
  const unsigned short* B1 = lds + 49152;

  f32x4 acc[8][4];
#pragma unroll
  for (int i = 0; i < 8; ++i)
#pragma unroll
    for (int j = 0; j < 4; ++j) acc[i][j] = (f32x4){0.f, 0.f, 0.f, 0.f};
  bf16x8 ar[4][2], br[4][2];

  // prologue: tile0 full -> buf0 (8 loads); tile1 B -> buf1 (4 loads)
  SA_(0, 0, 0); SA_(0, 0, 1); SA_(0, 0, 2); SA_(0, 0, 3);
  SB_(0, 0, 0); SB_(0, 0, 1); SB_(0, 0, 2); SB_(0, 0, 3);
  SB_(1, 1, 0); SB_(1, 1, 1); SB_(1, 1, 2); SB_(1, 1, 3);
  asm volatile("s_waitcnt vmcnt(4)" ::: "memory");  // tile0 landed; tile1-B in flight
  QKV_BAR();

  // 16 K-tiles of 64; iteration i computes tiles 2i (buf0) and 2i+1 (buf1).
  // Staging (2 loads/phase): ph0/1 A(2i+1)->buf1, ph2/3 B(2i+2)->buf0,
  // ph4/5 A(2i+2)->buf0, ph6/7 B(2i+3)->buf1.
  // vmcnt ledger at ph3-wait: [B1:4][A1:4][B0new:4] -> vmcnt(4) drains A1+B1
  // (read ph4-7); at ph7-wait: [B0n:4][A0n:4][B1n:4] -> vmcnt(4) drains
  // A0n+B0n (read next ph0). Prologue vmcnt(4) drains tile0's 8.
#pragma unroll 1
  for (int i = 0; i < 8; ++i) {
    const int tn = 2 * i + 2;
    const bool st = (i < 7);
    // ph0: buf0 (mh0,c0); loads br[.][0]
    qkv_ds_a<0, 0>(A0, wm, quad, l15, ar);
    qkv_ds_b<0>(B0, wn, quad, l15, br);
    SA_(1, 2 * i + 1, 0); SA_(1, 2 * i + 1, 1);
    QKV_BAR(); QKV_LGKM0();
    __builtin_amdgcn_s_setprio(1); qkv_mf<0, 0>(ar, br, acc); __builtin_amdgcn_s_setprio(0);
    QKV_BAR();
    // ph1: buf0 (mh0,c1); loads br[.][1] — last LDS reads of B0
    qkv_ds_a<0, 1>(A0, wm, quad, l15, ar);
    qkv_ds_b<1>(B0, wn, quad, l15, br);
    SA_(1, 2 * i + 1, 2); SA_(1, 2 * i + 1, 3);
    QKV_BAR(); QKV_LGKM0();
    __builtin_amdgcn_s_setprio(1); qkv_mf<0, 1>(ar, br, acc); __builtin_amdgcn_s_setprio(0);
    QKV_BAR();
    // ph2: buf0 (mh1,c0); br reused from regs; B0 free -> stage into it
    qkv_ds_a<1, 0>(A0, wm, quad, l15, ar);
    if (st) { SB_(0, tn, 0); SB_(0, tn, 1); }
    QKV_BAR(); QKV_LGKM0();
    __builtin_amdgcn_s_setprio(1); qkv_mf<1, 0>(ar, br, acc); __builtin_amdgcn_s_setprio(0);
    QKV_BAR();
    // ph3: buf0 (mh1,c1); counted wait
    qkv_ds_a<1, 1>(A0, wm, quad, l15, ar);
    if (st) { SB_(0, tn, 2); SB_(0, tn, 3); }
    QKV_BAR(); QKV_LGKM0();
    __builtin_amdgcn_s_setprio(1); qkv_mf<1, 1>(ar, br, acc); __builtin_amdgcn_s_setprio(0);
    if (st) asm volatile("s_waitcnt vmcnt(4)" ::: "memory");
    else    asm volatile("s_waitcnt vmcnt(0)" ::: "memory");  // last iter: drain all
    QKV_BAR();
    // ph4: buf1 (mh0,c0); A(buf0) free (reads done ph3)
    qkv_ds_a<0, 0>(A1, wm, quad, l15, ar);
    qkv_ds_b<0>(B1, wn, quad, l15, br);
    if (st) { SA_(0, tn, 0); SA_(0, tn, 1); }
    QKV_BAR(); QKV_LGKM0();
    __builtin_amdgcn_s_setprio(1); qkv_mf<0, 0>(ar, br, acc); __builtin_amdgcn_s_setprio(0);
    QKV_BAR();
    // ph5: buf1 (mh0,c1) — last LDS reads of B1
    qkv_ds_a<0, 1>(A1, wm, quad, l15, ar);
    qkv_ds_b<1>(B1, wn, quad, l15, br);
    if (st) { SA_(0, tn, 2); SA_(0, tn, 3); }
    QKV_BAR(); QKV_LGKM0();
    __builtin_amdgcn_s_setprio(1); qkv_mf<0, 1>(ar, br, acc); __builtin_amdgcn_s_setprio(0);
    QKV_BAR();
    // ph6: buf1 (mh1,c0); br reused; B1 free -> stage into it
    qkv_ds_a<1, 0>(A1, wm, quad, l15, ar);
    if (st) { SB_(1, tn + 1, 0); SB_(1, tn + 1, 1); }
    QKV_BAR(); QKV_LGKM0();
    __builtin_amdgcn_s_setprio(1); qkv_mf<1, 0>(ar, br, acc); __builtin_amdgcn_s_setprio(0);
    QKV_BAR();
    // ph7: buf1 (mh1,c1); counted wait
    qkv_ds_a<1, 1>(A1, wm, quad, l15, ar);
    if (st) { SB_(1, tn + 1, 2); SB_(1, tn + 1, 3); }
    QKV_BAR(); QKV_LGKM0();
    __builtin_amdgcn_s_setprio(1); qkv_mf<1, 1>(ar, br, acc); __builtin_amdgcn_s_setprio(0);
    asm volatile("s_waitcnt vmcnt(4)" ::: "memory");
    QKV_BAR();
  }

  // epilogue: C[row = m0+wm*128+mi*16+quad*4+r][col = n0+wn*64+nj*16+l15]
#pragma unroll
  for (int nj = 0; nj < 4; ++nj) {
    const int n_abs = n0 + wn * 64 + nj * 16 + l15;  // 0..3071
    const int type = n_abs >> 10;                    // 0=Q 1=K 2=V
    const int n_in = n_abs & 1023;
    const int h = n_in >> 6, kh = n_in & 63;
    const float bv = ((type == 0) ? bQ : (type == 1) ? bK : bV)[n_in];
#pragma unroll
    for (int mi = 0; mi < 8; ++mi) {
      const int mb = m0 + wm * 128 + mi * 16 + quad * 4;
      const int b = mb >> 11, tb = mb & 2047;
      if (type == 2) {
        uint2 pk;
        pk.x = (unsigned)f2bf(acc[mi][nj][0] + bv) |
               ((unsigned)f2bf(acc[mi][nj][1] + bv) << 16);
        pk.y = (unsigned)f2bf(acc[mi][nj][2] + bv) |
               ((unsigned)f2bf(acc[mi][nj][3] + bv) << 16);
        *(uint2*)(Vpg + ((size_t)(b * 16 + h) * 64 + kh) * 1024 + (tb >> 1)) = pk;
      } else {
        unsigned short* dst =
            ((type == 0) ? Qg : Kg) + ((size_t)(b * 16 + h) * 2048 + tb) * 64 + kh;
        // Q pre-scaled by 1/sqrt(Dh) * log2(e) so flash uses exp2 directly
        const float sc = (type == 0) ? 0.18033688011112042f : 1.0f;
        dst[0]   = f2bf((acc[mi][nj][0] + bv) * sc);
        dst[64]  = f2bf((acc[mi][nj][1] + bv) * sc);
        dst[128] = f2bf((acc[mi][nj][2] + bv) * sc);
        dst[192] = f2bf((acc[mi][nj][3] + bv) * sc);
      }
    }
  }
}

#undef SA_
#undef SB_
#undef QKV_BAR
#undef QKV_LGKM0

// ---------------- flash attention (R9 form: 256 thr, 4 waves x 64 q) --------
__device__ __forceinline__ void stage_kv(const unsigned short* __restrict__ Kb,
                                         const unsigned int* __restrict__ Vb,
                                         unsigned short* smem, int tid, int s0, int b) {
#pragma unroll
  for (int u = 0; u < 2; ++u) {
    int s = u * 256 + tid, row = s >> 3, g = (s & 7) ^ rho(row);
    gl_lds16(Kb + (size_t)(s0 + row) * 64 + g * 8, smem + b * 8192 + s * 8);
    gl_lds16(Vb + (size_t)row * 1024 + (s0 >> 1) + g * 4,
             smem + b * 8192 + 4096 + s * 8);
  }
}

// block: 256 q-rows of one (b,h); wave owns 64 q; k-tiles of 64, double-buffered.
// grid (bh=64, qt=8): all q-tiles of one bh on one XCD -> K/V L2-local.
__global__ __launch_bounds__(256, 2) void flash_attn(
    const unsigned short* __restrict__ Qg, const unsigned short* __restrict__ Kg,
    const unsigned int* __restrict__ Vpg, unsigned short* __restrict__ OH) {
  __shared__ unsigned short smem[16384];  // 32KB: [K0 8K][V0 8K][K1 8K][V1 8K]
  const int tid = threadIdx.x, lane = tid & 63, w = tid >> 6;
  const int quad = lane >> 4, l15 = lane & 15;
  const int bh = blockIdx.x, qt = blockIdx.y;

  const unsigned short* Qb = Qg + ((size_t)bh * 2048 + qt * 256) * 64;
  const unsigned short* Kb = Kg + (size_t)bh * 2048 * 64;
  const unsigned int*  Vb = Vpg + (size_t)bh * 64 * 1024;

  // stage Q (256 rows = 32KB, whole smem) — dead before tile 0
#pragma unroll
  for (int u = 0; u < 8; ++u) {
    int s = u * 256 + tid, row = s >> 3;
    gl_lds16(Qb + row * 64 + ((s & 7) ^ (row & 7)) * 8, smem + s * 8);
  }
  __syncthreads();

  bf16x8 qf[4][2];  // B-operand Q frags, hoisted for whole kernel
#pragma unroll
  for (int qi = 0; qi < 4; ++qi) {
    int row = w * 64 + qi * 16 + l15;
#pragma unroll
    for (int c = 0; c < 2; ++c)
      qf[qi][c] = *(const bf16x8*)(smem + row * 64 + (((c * 4 + quad) ^ (row & 7)) * 8));
  }
  __syncthreads();  // all waves done reading Q; safe to overwrite with K0/V0

  stage_kv(Kb, Vb, smem, tid, 0, 0);

  f32x4 o[4][4];
  float l_part[4] = {0.f, 0.f, 0.f, 0.f};
#pragma unroll
  for (int qi = 0; qi < 4; ++qi)
#pragma unroll
    for (int nj = 0; nj < 4; ++nj) o[qi][nj] = (f32x4){0.f, 0.f, 0.f, 0.f};

  for (int t = 0; t < 32; ++t) {
    __syncthreads();  // drains tile-t staging
    if (t < 31) stage_kv(Kb, Vb, smem, tid, (t + 1) * 64, (t + 1) & 1);
    const unsigned short* Kd = smem + (t & 1) * 8192;
    const unsigned short* Vd = Kd + 4096;

#pragma unroll
    for (int blk = 0; blk < 2; ++blk) {
      // V B-frags: Vt[dh = nj*16+l15][s = blk*32 + quad*8 .. +7] — one b128 each
      bf16x8 vb[4];
#pragma unroll
      for (int nj = 0; nj < 4; ++nj) {
        int vrow = nj * 16 + l15;
        vb[nj] = *(const bf16x8*)(Vd + vrow * 64 + (((blk * 4 + quad) ^ rho(vrow)) * 8));
      }
      union { unsigned u[4]; bf16x8 v; } pa[4];
#pragma unroll
      for (int v = 0; v < 2; ++v) {
        // permuted K rows: C/D row m maps to s = blk*32 + 8*quad + 4*v + reg
        int krow = blk * 32 + 8 * (l15 >> 2) + 4 * v + (l15 & 3);
        const unsigned short* kr = Kd + krow * 64;
        bf16x8 ka0 = *(const bf16x8*)(kr + ((quad ^ rho(krow)) * 8));
        bf16x8 ka1 = *(const bf16x8*)(kr + (((4 + quad) ^ rho(krow)) * 8));
#pragma unroll
        for (int qi = 0; qi < 4; ++qi) {
          f32x4 S = (f32x4){0.f, 0.f, 0.f, 0.f};
          S = MFMA32(ka0, qf[qi][0], S, 0, 0, 0);
          S = MFMA32(ka1, qf[qi][1], S, 0, 0, 0);
          float e0 = EXP2(S[0]), e1 = EXP2(S[1]), e2 = EXP2(S[2]), e3 = EXP2(S[3]);
          l_part[qi] += (e0 + e1) + (e2 + e3);
          pa[qi].u[2 * v] = packbf2(e0, e1);
          pa[qi].u[2 * v + 1] = packbf2(e2, e3);
        }
      }
#pragma unroll
      for (int nj = 0; nj < 4; ++nj)
#pragma unroll
        for (int qi = 0; qi < 4; ++qi)
          o[qi][nj] = MFMA32(pa[qi].v, vb[nj], o[qi][nj], 0, 0, 0);
    }
  }

  // l: cross-quad reduce once; normalize + store
  const int b = bh >> 4, h = bh & 15;
#pragma unroll
  for (int qi = 0; qi < 4; ++qi) {
    float l = l_part[qi];
    l += __shfl_xor(l, 16);
    l += __shfl_xor(l, 32);
    float linv = 1.0f / l;
#pragma unroll
    for (int r = 0; r < 4; ++r) {
      float lr = __shfl(linv, 4 * quad + r);  // l of q_local = 4*quad + r
      int trow = qt * 256 + w * 64 + qi * 16 + 4 * quad + r;
#pragma unroll
      for (int nj = 0; nj < 4; ++nj) {
        int col = h * 64 + nj * 16 + l15;
        OH[((size_t)b * 2048 + trow) * 1024 + col] = f2bf(o[qi][nj][r] * lr);
      }
    }
  }
}

// ---------------- output projection (128x64 tile, R9 form) ----------------
__global__ __launch_bounds__(256) void gemm_o(
    const unsigned short* __restrict__ OHm, const unsigned short* __restrict__ Wot,
    const float* __restrict__ bO, float* __restrict__ Out) {
  __shared__ unsigned short As[128 * 64];  // 16KB
  __shared__ unsigned short Bs[64 * 64];   // 8KB
  const int tid = threadIdx.x, lane = tid & 63, w = tid >> 6;
  const int quad = lane >> 4, l15 = lane & 15;
  const int wm = w & 1, wn = w >> 1;
  const int m0 = blockIdx.x * 128, n0 = blockIdx.y * 64;
  f32x4 acc[4][2];
#pragma unroll
  for (int i = 0; i < 4; ++i)
#pragma unroll
    for (int j = 0; j < 2; ++j) acc[i][j] = (f32x4){0.f, 0.f, 0.f, 0.f};

  for (int k0 = 0; k0 < 1024; k0 += 64) {
    __syncthreads();
#pragma unroll
    for (int u = 0; u < 4; ++u) {
      int s = u * 256 + tid, row = s >> 3;
      int cl = ((s & 7) ^ (row & 7)) * 8;
      gl_lds16(OHm + (size_t)(m0 + row) * 1024 + k0 + cl, As + s * 8);
    }
#pragma unroll
    for (int u = 0; u < 2; ++u) {
      int s = u * 256 + tid, row = s >> 3;
      int cl = ((s & 7) ^ (row & 7)) * 8;
      gl_lds16(Wot + (size_t)(n0 + row) * 1024 + k0 + cl, Bs + s * 8);
    }
    __syncthreads();
    bf16x8 af[4][2], bfr[2][2];
#pragma unroll
    for (int i = 0; i < 4; ++i) {
      int ra = wm * 64 + i * 16 + l15;
#pragma unroll
      for (int c = 0; c < 2; ++c)
        af[i][c] = *(const bf16x8*)(As + ra * 64 + (((c * 4 + quad) ^ (ra & 7)) * 8));
    }
#pragma unroll
    for (int j = 0; j < 2; ++j) {
      int rb = wn * 32 + j * 16 + l15;
#pragma unroll
      for (int c = 0; c < 2; ++c)
        bfr[j][c] = *(const bf16x8*)(Bs + rb * 64 + (((c * 4 + quad) ^ (rb & 7)) * 8));
    }
#pragma unroll
    for (int mi = 0; mi < 4; ++mi)
#pragma unroll
      for (int nj = 0; nj < 2; ++nj) {
        acc[mi][nj] = MFMA32(af[mi][0], bfr[nj][0], acc[mi][nj], 0, 0, 0);
        acc[mi][nj] = MFMA32(af[mi][1], bfr[nj][1], acc[mi][nj], 0, 0, 0);
      }
  }

#pragma unroll
  for (int nj = 0; nj < 2; ++nj) {
    const int n = n0 + wn * 32 + nj * 16 + l15;
    const float bv = bO[n];
#pragma unroll
    for (int mi = 0; mi < 4; ++mi) {
      const int mb = m0 + wm * 64 + mi * 16 + quad * 4;
#pragma unroll
      for (int r = 0; r < 4; ++r)
        Out[(size_t)(mb + r) * 1024 + n] = acc[mi][nj][r] + bv;
    }
  }
}

// ---------------- launch ----------------
extern "C" void kernel_launch(void* const* d_in, const int* in_sizes, int n_in,
                              void* d_out, int out_size, void* d_ws, size_t ws_size,
                              hipStream_t stream) {
  const float* x  = (const float*)d_in[0];
  const float* WQ = (const float*)d_in[1];
  const float* bQ = (const float*)d_in[2];
  const float* WK = (const float*)d_in[3];
  const float* bK = (const float*)d_in[4];
  const float* WV = (const float*)d_in[5];
  const float* bV = (const float*)d_in[6];
  const float* WO = (const float*)d_in[7];
  const float* bO = (const float*)d_in[8];
  float* out = (float*)d_out;

  char* ws = (char*)d_ws;
  unsigned short* Xb   = (unsigned short*)(ws);                // 16 MB
  unsigned short* OH   = (unsigned short*)(ws);                // alias (Xb dead)
  unsigned short* Wqkv = (unsigned short*)(ws + 16777216);     // 6 MB
  unsigned short* Wot  = (unsigned short*)(ws + 23068672);     // 2 MB
  unsigned short* Qg   = (unsigned short*)(ws + 25165824);     // 16 MB
  unsigned short* Kg   = (unsigned short*)(ws + 41943040);     // 16 MB
  unsigned int*   Vpg  = (unsigned int*)  (ws + 58720256);     // 16 MB

  prep_all<<<6144, 256, 0, stream>>>(x, WQ, WK, WV, WO, Xb, Wqkv, Wot);

  dim3 g1(32, 12);
  gemm_qkv<<<g1, 512, 0, stream>>>(Xb, Wqkv, bQ, bK, bV, Qg, Kg, Vpg);
  dim3 g2(64, 8);
  flash_attn<<<g2, 256, 0, stream>>>(Qg, Kg, Vpg, OH);
  dim3 g3(64, 16);
  gemm_o<<<g3, 256, 0, stream>>>(OH, Wot, bO, out);
}

// Round 8
// 252.428 us; speedup vs baseline: 1.1218x; 1.0405x over previous
//
#include <hip/hip_runtime.h>
#include <stdint.h>

// Attention fwd: B=4 T=2048 D=1024 H=16 Dh=64.
// R16 = exact R9 baseline (best measured 252.9us) + ONE lever: T5 setprio
//   around flash's PV MFMA cluster (m191: +4-7% on attn with inter-block
//   role diversity; flash has 2 unsynced blocks/CU).
// qkv 256x256 attempts R13-R15 all failed (race / 128-VGPR spill: WRITE 97MB,
//   MfmaUtil 24); 256x192 @ 112 VGPR is the geometry that fits the budget.

typedef __attribute__((ext_vector_type(8))) short bf16x8;
typedef __attribute__((ext_vector_type(4))) float f32x4;

#define MFMA32 __builtin_amdgcn_mfma_f32_16x16x32_bf16

#if __has_builtin(__builtin_amdgcn_exp2f)
#define EXP2(x) __builtin_amdgcn_exp2f(x)
#else
#define EXP2(x) exp2f(x)   // host pass only
#endif

__device__ __forceinline__ unsigned short f2bf(float f) {
  union { float f; unsigned int u; } v; v.f = f;
  unsigned int r = v.u + 0x7FFFu + ((v.u >> 16) & 1u);  // RNE
  return (unsigned short)(r >> 16);
}

__device__ __forceinline__ void gl_lds16(const void* g, void* l) {
  __builtin_amdgcn_global_load_lds(
      (const __attribute__((address_space(1))) unsigned int*)g,
      (__attribute__((address_space(3))) unsigned int*)l, 16, 0, 0);
}

// truncating pack of two positive fp32 -> one u32 (two bf16)
__device__ __forceinline__ unsigned packbf2(float lo, float hi) {
  union { float f; unsigned u; } a, b; a.f = lo; b.f = hi;
  return __builtin_amdgcn_perm(b.u, a.u, 0x07060302u);
}

// LDS chunk swizzle for K/V tiles (conflict-free for permuted-row b128 reads)
__device__ __forceinline__ int rho(int r) { return (r & 3) | ((r >> 1) & 4); }

// ---------------- merged prep kernel ----------------
__device__ __forceinline__ void conv8(const float* __restrict__ src,
                                      unsigned short* __restrict__ dst, int i) {
  const float4* sp = (const float4*)src;
  float4 a = sp[2 * i], b = sp[2 * i + 1];
  union { unsigned short u[8]; uint4 v; } o;
  o.u[0] = f2bf(a.x); o.u[1] = f2bf(a.y); o.u[2] = f2bf(a.z); o.u[3] = f2bf(a.w);
  o.u[4] = f2bf(b.x); o.u[5] = f2bf(b.y); o.u[6] = f2bf(b.z); o.u[7] = f2bf(b.w);
  ((uint4*)dst)[i] = o.v;
}

__global__ __launch_bounds__(256) void prep_all(
    const float* __restrict__ x, const float* __restrict__ WQ,
    const float* __restrict__ WK, const float* __restrict__ WV,
    const float* __restrict__ WO, unsigned short* __restrict__ Xb,
    unsigned short* __restrict__ Wqkv, unsigned short* __restrict__ Wot) {
  const int bx = blockIdx.x, t = threadIdx.x;
  if (bx < 4096) {
    conv8(x, Xb, bx * 256 + t);
  } else if (bx < 4608) {
    conv8(WQ, Wqkv, (bx - 4096) * 256 + t);
  } else if (bx < 5120) {
    conv8(WK, Wqkv + 1048576, (bx - 4608) * 256 + t);
  } else if (bx < 5632) {
    conv8(WV, Wqkv + 2097152, (bx - 5120) * 256 + t);
  } else {
    // W_O [16][1024][64] fp32 -> Wot [d][h*64+k] bf16
    int tid = (bx - 5632) * 256 + t;
    int h = tid >> 13, rem = tid & 8191;
    int d = rem >> 3, c = rem & 7;
    const float4* sp = (const float4*)(WO + (size_t)h * 65536 + d * 64 + c * 8);
    float4 a = sp[0], e = sp[1];
    union { unsigned short u[8]; uint4 v; } o;
    o.u[0] = f2bf(a.x); o.u[1] = f2bf(a.y); o.u[2] = f2bf(a.z); o.u[3] = f2bf(a.w);
    o.u[4] = f2bf(e.x); o.u[5] = f2bf(e.y); o.u[6] = f2bf(e.z); o.u[7] = f2bf(e.w);
    *(uint4*)(Wot + (size_t)d * 1024 + h * 64 + c * 8) = o.v;
  }
}

// ---------------- QKV projection: 256x192 tile, 8-phase pipelined ----------------
// LDS ushort layout: A0 @0 (256x64), B0 @16384 (192x64), A1 @28672, B1 @45056.
// Swizzle: element (row,k) at row*64 + ((k>>3)^(row&7))*8 + (k&7)  (involution,
// staged via pre-swizzled global source; measured 0 bank conflicts).

template <int MH, int C>
__device__ __forceinline__ void qkv_ds_a(const unsigned short* A, int wm, int quad,
                                         int l15, bf16x8 ar[4][2]) {
#pragma unroll
  for (int ii = 0; ii < 4; ++ii) {
    int ra = wm * 128 + MH * 64 + ii * 16 + l15;
    ar[ii][C] = *(const bf16x8*)(A + ra * 64 + (((C * 4 + quad) ^ (ra & 7)) * 8));
  }
}

template <int C>
__device__ __forceinline__ void qkv_ds_b(const unsigned short* B, int wn, int quad,
                                         int l15, bf16x8 br[3][2]) {
#pragma unroll
  for (int nj = 0; nj < 3; ++nj) {
    int rb = wn * 48 + nj * 16 + l15;
    br[nj][C] = *(const bf16x8*)(B + rb * 64 + (((C * 4 + quad) ^ (rb & 7)) * 8));
  }
}

template <int MH, int C>
__device__ __forceinline__ void qkv_mf(const bf16x8 ar[4][2], const bf16x8 br[3][2],
                                       f32x4 acc[8][3]) {
#pragma unroll
  for (int ii = 0; ii < 4; ++ii)
#pragma unroll
    for (int nj = 0; nj < 3; ++nj)
      acc[MH * 4 + ii][nj] =
          MFMA32(ar[ii][C], br[nj][C], acc[MH * 4 + ii][nj], 0, 0, 0);
}

#define QKV_BAR() __builtin_amdgcn_s_barrier()
#define QKV_LGKM0() asm volatile("s_waitcnt lgkmcnt(0)" ::: "memory")
#define SA_(bb, kt, u) \
  gl_lds16(Xb + (size_t)aoff[u] + (size_t)(kt) * 64, lds + (bb)*28672 + adst[u])
#define SB_(bb, kt, u) \
  gl_lds16(Wqkv + (size_t)boff[u] + (size_t)(kt) * 64, lds + (bb)*28672 + 16384 + bdst[u])

__global__ __launch_bounds__(512, 2) void gemm_qkv(
    const unsigned short* __restrict__ Xb, const unsigned short* __restrict__ Wqkv,
    const float* __restrict__ bQ, const float* __restrict__ bK,
    const float* __restrict__ bV, unsigned short* __restrict__ Qg,
    unsigned short* __restrict__ Kg, unsigned int* __restrict__ Vpg) {
  __shared__ unsigned short lds[57344];  // 112 KB
  const int tid = threadIdx.x, lane = tid & 63, w = tid >> 6;
  const int quad = lane >> 4, l15 = lane & 15;
  const int wm = w >> 2, wn = w & 3;
  const int m0 = blockIdx.x * 256, n0 = blockIdx.y * 192;

  // staging source offsets (inverse-swizzled global address; LDS dest linear)
  int aoff[4], adst[4];
#pragma unroll
  for (int u = 0; u < 4; ++u) {
    int s = u * 512 + tid, row = s >> 3;
    aoff[u] = (m0 + row) * 1024 + (((s & 7) ^ (row & 7)) * 8);
    adst[u] = s * 8;
  }
  int boff[3], bdst[3];
#pragma unroll
  for (int u = 0; u < 3; ++u) {
    int s = u * 512 + tid, row = s >> 3;
    boff[u] = (n0 + row) * 1024 + (((s & 7) ^ (row & 7)) * 8);
    bdst[u] = s * 8;
  }

  const unsigned short* A0 = lds;
  const unsigned short* B0 = lds + 16384;
  const unsigned short* A1 = lds + 28672;
  const unsigned short* B1 = lds + 45056;

  f32x4 acc[8][3];
#pragma unroll
  for (int i = 0; i < 8; ++i)
#pragma unroll
    for (int j = 0; j < 3; ++j) acc[i][j] = (f32x4){0.f, 0.f, 0.f, 0.f};
  bf16x8 ar[4][2], br[3][2];

  // prologue: tile0 full -> buf0 (7 loads); tile1 B -> buf1 (3 loads)
  SA_(0, 0, 0); SA_(0, 0, 1); SA_(0, 0, 2); SA_(0, 0, 3);
  SB_(0, 0, 0); SB_(0, 0, 1); SB_(0, 0, 2);
  SB_(1, 1, 0); SB_(1, 1, 1); SB_(1, 1, 2);
  asm volatile("s_waitcnt vmcnt(3)" ::: "memory");  // tile0 landed; tile1-B in flight
  QKV_BAR();

  // 16 K-tiles of 64; iteration i computes tiles 2i (buf0) and 2i+1 (buf1).
  // Staging map (1 half-tile/phase): ph0/1 A(2i+1)->buf1, ph2/3 B(2i+2)->buf0,
  // ph4/5 A(2i+2)->buf0, ph6/7 B(2i+3)->buf1. Counted waits at end of ph3/ph7.
#pragma unroll 1
  for (int i = 0; i < 8; ++i) {
    const int tn = 2 * i + 2;
    const bool st = (i < 7);
    // ph0: buf0 (mh0,c0)
    qkv_ds_a<0, 0>(A0, wm, quad, l15, ar);
    qkv_ds_b<0>(B0, wn, quad, l15, br);
    SA_(1, 2 * i + 1, 0); SA_(1, 2 * i + 1, 1);
    QKV_BAR(); QKV_LGKM0();
    __builtin_amdgcn_s_setprio(1); qkv_mf<0, 0>(ar, br, acc); __builtin_amdgcn_s_setprio(0);
    QKV_BAR();
    // ph1: buf0 (mh0,c1)
    qkv_ds_a<0, 1>(A0, wm, quad, l15, ar);
    qkv_ds_b<1>(B0, wn, quad, l15, br);
    SA_(1, 2 * i + 1, 2); SA_(1, 2 * i + 1, 3);
    QKV_BAR(); QKV_LGKM0();
    __builtin_amdgcn_s_setprio(1); qkv_mf<0, 1>(ar, br, acc); __builtin_amdgcn_s_setprio(0);
    QKV_BAR();
    // ph2: buf0 (mh1,c0); B(buf0) free (reads done ph1)
    qkv_ds_a<1, 0>(A0, wm, quad, l15, ar);
    if (st) { SB_(0, tn, 0); SB_(0, tn, 1); }
    QKV_BAR(); QKV_LGKM0();
    __builtin_amdgcn_s_setprio(1); qkv_mf<1, 0>(ar, br, acc); __builtin_amdgcn_s_setprio(0);
    QKV_BAR();
    // ph3: buf0 (mh1,c1); counted wait: tile 2i+1 (buf1) must be landed past here
    qkv_ds_a<1, 1>(A0, wm, quad, l15, ar);
    if (st) SB_(0, tn, 2);
    QKV_BAR(); QKV_LGKM0();
    __builtin_amdgcn_s_setprio(1); qkv_mf<1, 1>(ar, br, acc); __builtin_amdgcn_s_setprio(0);
    if (st) asm volatile("s_waitcnt vmcnt(3)" ::: "memory");  // leaves ph2/3 B in flight
    else    asm volatile("s_waitcnt vmcnt(0)" ::: "memory");  // last iter: drain all
    QKV_BAR();
    // ph4: buf1 (mh0,c0); A(buf0) free (reads done ph3)
    qkv_ds_a<0, 0>(A1, wm, quad, l15, ar);
    qkv_ds_b<0>(B1, wn, quad, l15, br);
    if (st) { SA_(0, tn, 0); SA_(0, tn, 1); }
    QKV_BAR(); QKV_LGKM0();
    __builtin_amdgcn_s_setprio(1); qkv_mf<0, 0>(ar, br, acc); __builtin_amdgcn_s_setprio(0);
    QKV_BAR();
    // ph5: buf1 (mh0,c1)
    qkv_ds_a<0, 1>(A1, wm, quad, l15, ar);
    qkv_ds_b<1>(B1, wn, quad, l15, br);
    if (st) { SA_(0, tn, 2); SA_(0, tn, 3); }
    QKV_BAR(); QKV_LGKM0();
    __builtin_amdgcn_s_setprio(1); qkv_mf<0, 1>(ar, br, acc); __builtin_amdgcn_s_setprio(0);
    QKV_BAR();
    // ph6: buf1 (mh1,c0); B(buf1) free (reads done ph5)
    qkv_ds_a<1, 0>(A1, wm, quad, l15, ar);
    if (st) { SB_(1, tn + 1, 0); SB_(1, tn + 1, 1); }
    QKV_BAR(); QKV_LGKM0();
    __builtin_amdgcn_s_setprio(1); qkv_mf<1, 0>(ar, br, acc); __builtin_amdgcn_s_setprio(0);
    QKV_BAR();
    // ph7: buf1 (mh1,c1); counted wait: tile 2i+2 (buf0) landed past here
    qkv_ds_a<1, 1>(A1, wm, quad, l15, ar);
    if (st) SB_(1, tn + 1, 2);
    QKV_BAR(); QKV_LGKM0();
    __builtin_amdgcn_s_setprio(1); qkv_mf<1, 1>(ar, br, acc); __builtin_amdgcn_s_setprio(0);
    asm volatile("s_waitcnt vmcnt(3)" ::: "memory");  // leaves ph6/7 B in flight
    QKV_BAR();
  }

  // epilogue: C[row = m0+wm*128+mi*16+quad*4+r][col = n0+wn*48+nj*16+l15]
#pragma unroll
  for (int nj = 0; nj < 3; ++nj) {
    const int n_abs = n0 + wn * 48 + nj * 16 + l15;  // 0..3071
    const int type = n_abs >> 10;                    // 0=Q 1=K 2=V
    const int n_in = n_abs & 1023;
    const int h = n_in >> 6, kh = n_in & 63;
    const float bv = ((type == 0) ? bQ : (type == 1) ? bK : bV)[n_in];
#pragma unroll
    for (int mi = 0; mi < 8; ++mi) {
      const int mb = m0 + wm * 128 + mi * 16 + quad * 4;
      const int b = mb >> 11, tb = mb & 2047;
      if (type == 2) {
        uint2 pk;
        pk.x = (unsigned)f2bf(acc[mi][nj][0] + bv) |
               ((unsigned)f2bf(acc[mi][nj][1] + bv) << 16);
        pk.y = (unsigned)f2bf(acc[mi][nj][2] + bv) |
               ((unsigned)f2bf(acc[mi][nj][3] + bv) << 16);
        *(uint2*)(Vpg + ((size_t)(b * 16 + h) * 64 + kh) * 1024 + (tb >> 1)) = pk;
      } else {
        unsigned short* dst =
            ((type == 0) ? Qg : Kg) + ((size_t)(b * 16 + h) * 2048 + tb) * 64 + kh;
        // Q pre-scaled by 1/sqrt(Dh) * log2(e) so flash uses exp2 directly
        const float sc = (type == 0) ? 0.18033688011112042f : 1.0f;
        dst[0]   = f2bf((acc[mi][nj][0] + bv) * sc);
        dst[64]  = f2bf((acc[mi][nj][1] + bv) * sc);
        dst[128] = f2bf((acc[mi][nj][2] + bv) * sc);
        dst[192] = f2bf((acc[mi][nj][3] + bv) * sc);
      }
    }
  }
}

#undef SA_
#undef SB_
#undef QKV_BAR
#undef QKV_LGKM0

// ---------------- flash attention (R9 form + T5 setprio on PV) --------------
__device__ __forceinline__ void stage_kv(const unsigned short* __restrict__ Kb,
                                         const unsigned int* __restrict__ Vb,
                                         unsigned short* smem, int tid, int s0, int b) {
#pragma unroll
  for (int u = 0; u < 2; ++u) {
    int s = u * 256 + tid, row = s >> 3, g = (s & 7) ^ rho(row);
    gl_lds16(Kb + (size_t)(s0 + row) * 64 + g * 8, smem + b * 8192 + s * 8);
    gl_lds16(Vb + (size_t)row * 1024 + (s0 >> 1) + g * 4,
             smem + b * 8192 + 4096 + s * 8);
  }
}

// block: 256 q-rows of one (b,h); wave owns 64 q; k-tiles of 64, double-buffered.
// grid (bh=64, qt=8): all q-tiles of one bh on one XCD -> K/V L2-local.
__global__ __launch_bounds__(256, 2) void flash_attn(
    const unsigned short* __restrict__ Qg, const unsigned short* __restrict__ Kg,
    const unsigned int* __restrict__ Vpg, unsigned short* __restrict__ OH) {
  __shared__ unsigned short smem[16384];  // 32KB: [K0 8K][V0 8K][K1 8K][V1 8K]
  const int tid = threadIdx.x, lane = tid & 63, w = tid >> 6;
  const int quad = lane >> 4, l15 = lane & 15;
  const int bh = blockIdx.x, qt = blockIdx.y;

  const unsigned short* Qb = Qg + ((size_t)bh * 2048 + qt * 256) * 64;
  const unsigned short* Kb = Kg + (size_t)bh * 2048 * 64;
  const unsigned int*  Vb = Vpg + (size_t)bh * 64 * 1024;

  // stage Q (256 rows = 32KB, whole smem) — dead before tile 0
#pragma unroll
  for (int u = 0; u < 8; ++u) {
    int s = u * 256 + tid, row = s >> 3;
    gl_lds16(Qb + row * 64 + ((s & 7) ^ (row & 7)) * 8, smem + s * 8);
  }
  __syncthreads();

  bf16x8 qf[4][2];  // B-operand Q frags, hoisted for whole kernel
#pragma unroll
  for (int qi = 0; qi < 4; ++qi) {
    int row = w * 64 + qi * 16 + l15;
#pragma unroll
    for (int c = 0; c < 2; ++c)
      qf[qi][c] = *(const bf16x8*)(smem + row * 64 + (((c * 4 + quad) ^ (row & 7)) * 8));
  }
  __syncthreads();  // all waves done reading Q; safe to overwrite with K0/V0

  stage_kv(Kb, Vb, smem, tid, 0, 0);

  f32x4 o[4][4];
  float l_part[4] = {0.f, 0.f, 0.f, 0.f};
#pragma unroll
  for (int qi = 0; qi < 4; ++qi)
#pragma unroll
    for (int nj = 0; nj < 4; ++nj) o[qi][nj] = (f32x4){0.f, 0.f, 0.f, 0.f};

  for (int t = 0; t < 32; ++t) {
    __syncthreads();  // drains tile-t staging
    if (t < 31) stage_kv(Kb, Vb, smem, tid, (t + 1) * 64, (t + 1) & 1);
    const unsigned short* Kd = smem + (t & 1) * 8192;
    const unsigned short* Vd = Kd + 4096;

#pragma unroll
    for (int blk = 0; blk < 2; ++blk) {
      // V B-frags: Vt[dh = nj*16+l15][s = blk*32 + quad*8 .. +7] — one b128 each
      bf16x8 vb[4];
#pragma unroll
      for (int nj = 0; nj < 4; ++nj) {
        int vrow = nj * 16 + l15;
        vb[nj] = *(const bf16x8*)(Vd + vrow * 64 + (((blk * 4 + quad) ^ rho(vrow)) * 8));
      }
      union { unsigned u[4]; bf16x8 v; } pa[4];
#pragma unroll
      for (int v = 0; v < 2; ++v) {
        // permuted K rows: C/D row m maps to s = blk*32 + 8*quad + 4*v + reg
        int krow = blk * 32 + 8 * (l15 >> 2) + 4 * v + (l15 & 3);
        const unsigned short* kr = Kd + krow * 64;
        bf16x8 ka0 = *(const bf16x8*)(kr + ((quad ^ rho(krow)) * 8));
        bf16x8 ka1 = *(const bf16x8*)(kr + (((4 + quad) ^ rho(krow)) * 8));
#pragma unroll
        for (int qi = 0; qi < 4; ++qi) {
          f32x4 S = (f32x4){0.f, 0.f, 0.f, 0.f};
          S = MFMA32(ka0, qf[qi][0], S, 0, 0, 0);
          S = MFMA32(ka1, qf[qi][1], S, 0, 0, 0);
          float e0 = EXP2(S[0]), e1 = EXP2(S[1]), e2 = EXP2(S[2]), e3 = EXP2(S[3]);
          l_part[qi] += (e0 + e1) + (e2 + e3);
          pa[qi].u[2 * v] = packbf2(e0, e1);
          pa[qi].u[2 * v + 1] = packbf2(e2, e3);
        }
      }
      // T5: boost this wave while it drains the 16-MFMA PV cluster (m191)
      __builtin_amdgcn_s_setprio(1);
#pragma unroll
      for (int nj = 0; nj < 4; ++nj)
#pragma unroll
        for (int qi = 0; qi < 4; ++qi)
          o[qi][nj] = MFMA32(pa[qi].v, vb[nj], o[qi][nj], 0, 0, 0);
      __builtin_amdgcn_s_setprio(0);
    }
  }

  // l: cross-quad reduce once; normalize + store
  const int b = bh >> 4, h = bh & 15;
#pragma unroll
  for (int qi = 0; qi < 4; ++qi) {
    float l = l_part[qi];
    l += __shfl_xor(l, 16);
    l += __shfl_xor(l, 32);
    float linv = 1.0f / l;
#pragma unroll
    for (int r = 0; r < 4; ++r) {
      float lr = __shfl(linv, 4 * quad + r);  // l of q_local = 4*quad + r
      int trow = qt * 256 + w * 64 + qi * 16 + 4 * quad + r;
#pragma unroll
      for (int nj = 0; nj < 4; ++nj) {
        int col = h * 64 + nj * 16 + l15;
        OH[((size_t)b * 2048 + trow) * 1024 + col] = f2bf(o[qi][nj][r] * lr);
      }
    }
  }
}

// ---------------- output projection (128x64 tile, R9 form) ----------------
__global__ __launch_bounds__(256) void gemm_o(
    const unsigned short* __restrict__ OHm, const unsigned short* __restrict__ Wot,
    const float* __restrict__ bO, float* __restrict__ Out) {
  __shared__ unsigned short As[128 * 64];  // 16KB
  __shared__ unsigned short Bs[64 * 64];   // 8KB
  const int tid = threadIdx.x, lane = tid & 63, w = tid >> 6;
  const int quad = lane >> 4, l15 = lane & 15;
  const int wm = w & 1, wn = w >> 1;
  const int m0 = blockIdx.x * 128, n0 = blockIdx.y * 64;
  f32x4 acc[4][2];
#pragma unroll
  for (int i = 0; i < 4; ++i)
#pragma unroll
    for (int j = 0; j < 2; ++j) acc[i][j] = (f32x4){0.f, 0.f, 0.f, 0.f};

  for (int k0 = 0; k0 < 1024; k0 += 64) {
    __syncthreads();
#pragma unroll
    for (int u = 0; u < 4; ++u) {
      int s = u * 256 + tid, row = s >> 3;
      int cl = ((s & 7) ^ (row & 7)) * 8;
      gl_lds16(OHm + (size_t)(m0 + row) * 1024 + k0 + cl, As + s * 8);
    }
#pragma unroll
    for (int u = 0; u < 2; ++u) {
      int s = u * 256 + tid, row = s >> 3;
      int cl = ((s & 7) ^ (row & 7)) * 8;
      gl_lds16(Wot + (size_t)(n0 + row) * 1024 + k0 + cl, Bs + s * 8);
    }
    __syncthreads();
    bf16x8 af[4][2], bfr[2][2];
#pragma unroll
    for (int i = 0; i < 4; ++i) {
      int ra = wm * 64 + i * 16 + l15;
#pragma unroll
      for (int c = 0; c < 2; ++c)
        af[i][c] = *(const bf16x8*)(As + ra * 64 + (((c * 4 + quad) ^ (ra & 7)) * 8));
    }
#pragma unroll
    for (int j = 0; j < 2; ++j) {
      int rb = wn * 32 + j * 16 + l15;
#pragma unroll
      for (int c = 0; c < 2; ++c)
        bfr[j][c] = *(const bf16x8*)(Bs + rb * 64 + (((c * 4 + quad) ^ (rb & 7)) * 8));
    }
#pragma unroll
    for (int mi = 0; mi < 4; ++mi)
#pragma unroll
      for (int nj = 0; nj < 2; ++nj) {
        acc[mi][nj] = MFMA32(af[mi][0], bfr[nj][0], acc[mi][nj], 0, 0, 0);
        acc[mi][nj] = MFMA32(af[mi][1], bfr[nj][1], acc[mi][nj], 0, 0, 0);
      }
  }

#pragma unroll
  for (int nj = 0; nj < 2; ++nj) {
    const int n = n0 + wn * 32 + nj * 16 + l15;
    const float bv = bO[n];
#pragma unroll
    for (int mi = 0; mi < 4; ++mi) {
      const int mb = m0 + wm * 64 + mi * 16 + quad * 4;
#pragma unroll
      for (int r = 0; r < 4; ++r)
        Out[(size_t)(mb + r) * 1024 + n] = acc[mi][nj][r] + bv;
    }
  }
}

// ---------------- launch ----------------
extern "C" void kernel_launch(void* const* d_in, const int* in_sizes, int n_in,
                              void* d_out, int out_size, void* d_ws, size_t ws_size,
                              hipStream_t stream) {
  const float* x  = (const float*)d_in[0];
  const float* WQ = (const float*)d_in[1];
  const float* bQ = (const float*)d_in[2];
  const float* WK = (const float*)d_in[3];
  const float* bK = (const float*)d_in[4];
  const float* WV = (const float*)d_in[5];
  const float* bV = (const float*)d_in[6];
  const float* WO = (const float*)d_in[7];
  const float* bO = (const float*)d_in[8];
  float* out = (float*)d_out;

  char* ws = (char*)d_ws;
  unsigned short* Xb   = (unsigned short*)(ws);                // 16 MB
  unsigned short* OH   = (unsigned short*)(ws);                // alias (Xb dead)
  unsigned short* Wqkv = (unsigned short*)(ws + 16777216);     // 6 MB
  unsigned short* Wot  = (unsigned short*)(ws + 23068672);     // 2 MB
  unsigned short* Qg   = (unsigned short*)(ws + 25165824);     // 16 MB
  unsigned short* Kg   = (unsigned short*)(ws + 41943040);     // 16 MB
  unsigned int*   Vpg  = (unsigned int*)  (ws + 58720256);     // 16 MB

  prep_all<<<6144, 256, 0, stream>>>(x, WQ, WK, WV, WO, Xb, Wqkv, Wot);

  dim3 g1(32, 16);
  gemm_qkv<<<g1, 512, 0, stream>>>(Xb, Wqkv, bQ, bK, bV, Qg, Kg, Vpg);
  dim3 g2(64, 8);
  flash_attn<<<g2, 256, 0, stream>>>(Qg, Kg, Vpg, OH);
  dim3 g3(64, 16);
  gemm_o<<<g3, 256, 0, stream>>>(OH, Wot, bO, out);
}